// Round 1
// baseline (681.921 us; speedup 1.0000x reference)
//
#include <hip/hip_runtime.h>
#include <math.h>

#define N_NODES 50000
#define N_EDGES 1600000
#define IN_F 256
#define OUT_F 64

// ---------------- K0: init (zero out, denom; reset umax) ----------------
__global__ __launch_bounds__(256) void k_init(float4* __restrict__ out4,
                                              unsigned* __restrict__ umax,
                                              float* __restrict__ denom) {
    int i = blockIdx.x * 256 + threadIdx.x;
    const int TOTAL4 = N_NODES * OUT_F / 4;  // 800000
    if (i < TOTAL4) out4[i] = make_float4(0.f, 0.f, 0.f, 0.f);
    if (i < N_NODES) { umax[i] = 0u; denom[i] = 0.f; }
}

// ---------------- K1: Wh = feature @ W^T, fused el/er ----------------
// block = 256 (4 waves). LDS holds W transposed (wT[k][c]). Each wave
// computes 4 rows x 64 cols; lane = output col. Feature loads are
// wave-uniform float4 (scalar-cached). Epilogue: wave-reduce el/er.
__global__ __launch_bounds__(256) void k_gemm(const float* __restrict__ feat,
                                              const float* __restrict__ W,
                                              const float* __restrict__ att_w,
                                              float* __restrict__ Wh,
                                              float* __restrict__ el,
                                              float* __restrict__ er) {
    __shared__ float wT[IN_F][OUT_F];  // 64 KB; wT[k][c] = W[c][k]
    const int tid = threadIdx.x;
    for (int idx = tid; idx < OUT_F * IN_F; idx += 256) {
        int c = idx >> 8;      // W row (output col)
        int k = idx & 255;     // W col (k)
        wT[k][c] = W[idx];
    }
    __syncthreads();

    const int lane = tid & 63;
    const int wave = tid >> 6;
    const float a_s = att_w[lane];        // a_src[c]
    const float a_d = att_w[64 + lane];   // a_dst[c]

    const int rbase = blockIdx.x * 16 + wave * 4;  // 3125 blocks * 16 rows = 50000
    if (rbase >= N_NODES) return;

    float acc0 = 0.f, acc1 = 0.f, acc2 = 0.f, acc3 = 0.f;
    const float* f0 = feat + (size_t)(rbase + 0) * IN_F;
    const float* f1 = feat + (size_t)(rbase + 1) * IN_F;
    const float* f2 = feat + (size_t)(rbase + 2) * IN_F;
    const float* f3 = feat + (size_t)(rbase + 3) * IN_F;

    #pragma unroll 4
    for (int k = 0; k < IN_F; k += 4) {
        float4 a = *(const float4*)(f0 + k);
        float4 b = *(const float4*)(f1 + k);
        float4 c = *(const float4*)(f2 + k);
        float4 d = *(const float4*)(f3 + k);
        float w0 = wT[k][lane], w1 = wT[k + 1][lane];
        float w2 = wT[k + 2][lane], w3 = wT[k + 3][lane];
        acc0 += a.x * w0 + a.y * w1 + a.z * w2 + a.w * w3;
        acc1 += b.x * w0 + b.y * w1 + b.z * w2 + b.w * w3;
        acc2 += c.x * w0 + c.y * w1 + c.z * w2 + c.w * w3;
        acc3 += d.x * w0 + d.y * w1 + d.z * w2 + d.w * w3;
    }

    float accs[4] = {acc0, acc1, acc2, acc3};
    #pragma unroll
    for (int j = 0; j < 4; ++j) {
        int r = rbase + j;
        Wh[(size_t)r * OUT_F + lane] = accs[j];
        float vs = accs[j] * a_s;
        float vd = accs[j] * a_d;
        #pragma unroll
        for (int off = 32; off; off >>= 1) {
            vs += __shfl_xor(vs, off);
            vd += __shfl_xor(vd, off);
        }
        if (lane == 0) { el[r] = vs; er[r] = vd; }
    }
}

// order-preserving float -> u32 mapping for atomic max
__device__ __forceinline__ unsigned f2u_ordered(float f) {
    unsigned b = __float_as_uint(f);
    return (f >= 0.f) ? (b | 0x80000000u) : ~b;
}
__device__ __forceinline__ float u2f_ordered(unsigned u) {
    unsigned b = (u & 0x80000000u) ? (u & 0x7fffffffu) : ~u;
    return __uint_as_float(b);
}

// ---------------- K2: edge pass 1 — e = leaky_relu(el[s]+er[d]); segmax ---
__global__ __launch_bounds__(256) void k_edge1(const int* __restrict__ src,
                                               const int* __restrict__ dst,
                                               const float* __restrict__ el,
                                               const float* __restrict__ er,
                                               float* __restrict__ ebuf,
                                               unsigned* __restrict__ umax) {
    int i = blockIdx.x * 256 + threadIdx.x;
    if (i >= N_EDGES) return;
    int s = src[i], d = dst[i];
    float e = el[s] + er[d];
    e = (e > 0.f) ? e : 0.2f * e;
    ebuf[i] = e;
    atomicMax(&umax[d], f2u_ordered(e));
}

// ---------------- K3: edge pass 2 — e_exp, segment_sum denom ----------------
__global__ __launch_bounds__(256) void k_edge2(const int* __restrict__ dst,
                                               float* __restrict__ ebuf,
                                               const unsigned* __restrict__ umax,
                                               float* __restrict__ denom) {
    int i = blockIdx.x * 256 + threadIdx.x;
    if (i >= N_EDGES) return;
    int d = dst[i];
    float m = u2f_ordered(umax[d]);
    float p = __expf(ebuf[i] - m);
    ebuf[i] = p;
    atomicAdd(&denom[d], p);
}

// ---------------- K4: edge pass 3 — out[d] += alpha * Wh[s] (wave/edge) ----
__global__ __launch_bounds__(256) void k_edge3(const int* __restrict__ src,
                                               const int* __restrict__ dst,
                                               const float* __restrict__ ebuf,
                                               const float* __restrict__ denom,
                                               const float* __restrict__ Wh,
                                               float* __restrict__ out) {
    int w = (blockIdx.x * 256 + threadIdx.x) >> 6;  // global wave id = edge id
    int lane = threadIdx.x & 63;
    if (w >= N_EDGES) return;
    int s = src[w], d = dst[w];
    float alpha = ebuf[w] / denom[d];  // denom >= 1 for any dst with edges
    atomicAdd(&out[(size_t)d * OUT_F + lane], alpha * Wh[(size_t)s * OUT_F + lane]);
}

// ---------------- K5: node epilogue — elu(out + Wh + bias) ----------------
__global__ __launch_bounds__(256) void k_node(const float4* __restrict__ Wh4,
                                              const float4* __restrict__ bias4,
                                              float4* __restrict__ out4) {
    int i = blockIdx.x * 256 + threadIdx.x;
    const int TOTAL4 = N_NODES * OUT_F / 4;  // 800000
    if (i >= TOTAL4) return;
    float4 o = out4[i];
    float4 w = Wh4[i];
    float4 b = bias4[i & 15];  // col group = (4*i) % 64
    float x0 = o.x + w.x + b.x;
    float x1 = o.y + w.y + b.y;
    float x2 = o.z + w.z + b.z;
    float x3 = o.w + w.w + b.w;
    o.x = (x0 > 0.f) ? x0 : expm1f(x0);
    o.y = (x1 > 0.f) ? x1 : expm1f(x1);
    o.z = (x2 > 0.f) ? x2 : expm1f(x2);
    o.w = (x3 > 0.f) ? x3 : expm1f(x3);
    out4[i] = o;
}

extern "C" void kernel_launch(void* const* d_in, const int* in_sizes, int n_in,
                              void* d_out, int out_size, void* d_ws, size_t ws_size,
                              hipStream_t stream) {
    const float* feat  = (const float*)d_in[0];
    const float* W     = (const float*)d_in[1];
    const float* att_w = (const float*)d_in[2];
    const float* bias  = (const float*)d_in[3];
    const int*   src   = (const int*)d_in[4];
    const int*   dst   = (const int*)d_in[5];
    float* out = (float*)d_out;

    // workspace layout (floats), all regions 256B-aligned
    float*    Wh    = (float*)d_ws;                 // 3,200,000
    float*    el    = Wh + 3200000;                 // 50,048
    float*    er    = el + 50048;                   // 50,048
    unsigned* umax  = (unsigned*)(er + 50048);      // 50,048
    float*    denom = (float*)(umax + 50048);       // 50,048
    float*    ebuf  = denom + 50048;                // 1,600,000

    k_init<<<3125, 256, 0, stream>>>((float4*)out, umax, denom);
    k_gemm<<<3125, 256, 0, stream>>>(feat, W, att_w, Wh, el, er);
    k_edge1<<<(N_EDGES + 255) / 256, 256, 0, stream>>>(src, dst, el, er, ebuf, umax);
    k_edge2<<<(N_EDGES + 255) / 256, 256, 0, stream>>>(dst, ebuf, umax, denom);
    k_edge3<<<(N_EDGES * 64) / 256, 256, 0, stream>>>(src, dst, ebuf, denom, Wh, out);
    k_node<<<3125, 256, 0, stream>>>((const float4*)Wh, (const float4*)bias, (float4*)out);
}

// Round 2
// 567.630 us; speedup vs baseline: 1.2013x; 1.2013x over previous
//
#include <hip/hip_runtime.h>
#include <math.h>

#define N_NODES 50000
#define N_EDGES 1600000
#define IN_F 256
#define OUT_F 64

// ---------------- K1: Wh = feature @ W^T, fused el/er ----------------
__global__ __launch_bounds__(256) void k_gemm(const float* __restrict__ feat,
                                              const float* __restrict__ W,
                                              const float* __restrict__ att_w,
                                              float* __restrict__ Wh,
                                              float* __restrict__ el,
                                              float* __restrict__ er) {
    __shared__ float wT[IN_F][OUT_F];  // 64 KB; wT[k][c] = W[c][k]
    const int tid = threadIdx.x;
    for (int idx = tid; idx < OUT_F * IN_F; idx += 256) {
        int c = idx >> 8;      // W row (output col)
        int k = idx & 255;     // W col (k)
        wT[k][c] = W[idx];
    }
    __syncthreads();

    const int lane = tid & 63;
    const int wave = tid >> 6;
    const float a_s = att_w[lane];        // a_src[c]
    const float a_d = att_w[64 + lane];   // a_dst[c]

    const int rbase = blockIdx.x * 16 + wave * 4;
    if (rbase >= N_NODES) return;

    float acc0 = 0.f, acc1 = 0.f, acc2 = 0.f, acc3 = 0.f;
    const float* f0 = feat + (size_t)(rbase + 0) * IN_F;
    const float* f1 = feat + (size_t)(rbase + 1) * IN_F;
    const float* f2 = feat + (size_t)(rbase + 2) * IN_F;
    const float* f3 = feat + (size_t)(rbase + 3) * IN_F;

    #pragma unroll 4
    for (int k = 0; k < IN_F; k += 4) {
        float4 a = *(const float4*)(f0 + k);
        float4 b = *(const float4*)(f1 + k);
        float4 c = *(const float4*)(f2 + k);
        float4 d = *(const float4*)(f3 + k);
        float w0 = wT[k][lane], w1 = wT[k + 1][lane];
        float w2 = wT[k + 2][lane], w3 = wT[k + 3][lane];
        acc0 += a.x * w0 + a.y * w1 + a.z * w2 + a.w * w3;
        acc1 += b.x * w0 + b.y * w1 + b.z * w2 + b.w * w3;
        acc2 += c.x * w0 + c.y * w1 + c.z * w2 + c.w * w3;
        acc3 += d.x * w0 + d.y * w1 + d.z * w2 + d.w * w3;
    }

    float accs[4] = {acc0, acc1, acc2, acc3};
    #pragma unroll
    for (int j = 0; j < 4; ++j) {
        int r = rbase + j;
        Wh[(size_t)r * OUT_F + lane] = accs[j];
        float vs = accs[j] * a_s;
        float vd = accs[j] * a_d;
        #pragma unroll
        for (int off = 32; off; off >>= 1) {
            vs += __shfl_xor(vs, off);
            vd += __shfl_xor(vd, off);
        }
        if (lane == 0) { el[r] = vs; er[r] = vd; }
    }
}

// ---------------- K2: histogram of dst ----------------
__global__ __launch_bounds__(256) void k_hist(const int* __restrict__ dst,
                                              int* __restrict__ hist) {
    int i = blockIdx.x * 256 + threadIdx.x;
    if (i >= N_EDGES) return;
    atomicAdd(&hist[dst[i]], 1);
}

// ---------------- K3: single-block exclusive scan (50000 elems) ----------
__global__ __launch_bounds__(1024) void k_scan(const int* __restrict__ hist,
                                               int* __restrict__ offs,
                                               int* __restrict__ cursor) {
    __shared__ int part[1024];
    const int CHUNK = 49;  // 1024*49 = 50176 >= 50000
    int t = threadIdx.x;
    int beg = t * CHUNK;
    int end = beg + CHUNK; if (end > N_NODES) end = N_NODES;
    int sum = 0;
    for (int i = beg; i < end; ++i) sum += hist[i];
    part[t] = sum;
    __syncthreads();
    // Hillis-Steele inclusive scan over 1024
    for (int d = 1; d < 1024; d <<= 1) {
        int v = (t >= d) ? part[t - d] : 0;
        __syncthreads();
        part[t] += v;
        __syncthreads();
    }
    int run = (t > 0) ? part[t - 1] : 0;
    for (int i = beg; i < end; ++i) {
        offs[i] = run;
        cursor[i] = run;
        run += hist[i];
    }
    if (t == 1023) offs[N_NODES] = part[1023];
}

// ---------------- K4: scatter src into CSR order ----------------
__global__ __launch_bounds__(256) void k_scatter(const int* __restrict__ src,
                                                 const int* __restrict__ dst,
                                                 int* __restrict__ cursor,
                                                 int* __restrict__ csr_src) {
    int i = blockIdx.x * 256 + threadIdx.x;
    if (i >= N_EDGES) return;
    int d = dst[i];
    int idx = atomicAdd(&cursor[d], 1);
    csr_src[idx] = src[i];
}

// ---------------- K5: per-node gather + softmax + aggregate + epilogue ---
__global__ __launch_bounds__(256) void k_aggr(const int* __restrict__ offs,
                                              const int* __restrict__ csr_src,
                                              const float* __restrict__ el,
                                              const float* __restrict__ er,
                                              const float* __restrict__ Wh,
                                              const float* __restrict__ bias,
                                              float* __restrict__ out) {
    int node = (blockIdx.x * 256 + threadIdx.x) >> 6;
    int lane = threadIdx.x & 63;
    if (node >= N_NODES) return;
    int beg = offs[node], end = offs[node + 1];
    float er_n = er[node];

    // pass 1: max over in-edges (lane-parallel over edges)
    float m = -1e30f;
    for (int j = beg + lane; j < end; j += 64) {
        float e = el[csr_src[j]] + er_n;
        e = (e > 0.f) ? e : 0.2f * e;
        m = fmaxf(m, e);
    }
    #pragma unroll
    for (int off = 32; off; off >>= 1) m = fmaxf(m, __shfl_xor(m, off));

    // pass 2: p = exp(e - m); acc += p * Wh[s]; den += p
    float acc = 0.f, den = 0.f;
    for (int j0 = beg; j0 < end; j0 += 64) {
        int j = j0 + lane;
        float p = 0.f;
        int s = 0;
        if (j < end) {
            s = csr_src[j];
            float e = el[s] + er_n;
            e = (e > 0.f) ? e : 0.2f * e;
            p = __expf(e - m);
        }
        den += p;
        int cnt = end - j0; if (cnt > 64) cnt = 64;
        #pragma unroll 4
        for (int k = 0; k < cnt; ++k) {
            float pk = __shfl(p, k);
            int   sk = __shfl(s, k);
            acc += pk * Wh[(size_t)sk * OUT_F + lane];
        }
    }
    #pragma unroll
    for (int off = 32; off; off >>= 1) den += __shfl_xor(den, off);

    float h = (end > beg) ? (acc / den) : 0.f;
    h += Wh[(size_t)node * OUT_F + lane] + bias[lane];
    out[(size_t)node * OUT_F + lane] = (h > 0.f) ? h : expm1f(h);
}

extern "C" void kernel_launch(void* const* d_in, const int* in_sizes, int n_in,
                              void* d_out, int out_size, void* d_ws, size_t ws_size,
                              hipStream_t stream) {
    const float* feat  = (const float*)d_in[0];
    const float* W     = (const float*)d_in[1];
    const float* att_w = (const float*)d_in[2];
    const float* bias  = (const float*)d_in[3];
    const int*   src   = (const int*)d_in[4];
    const int*   dst   = (const int*)d_in[5];
    float* out = (float*)d_out;

    // workspace layout (4-byte words), regions padded to 256B multiples
    float* Wh      = (float*)d_ws;            // 3,200,000
    float* el      = Wh + 3200000;            // 50,048
    float* er      = el + 50048;              // 50,048
    int*   hist    = (int*)(er + 50048);      // 50,048
    int*   offs    = hist + 50048;            // 50,064 (needs 50001)
    int*   cursor  = offs + 50064;            // 50,048
    int*   csr_src = cursor + 50048;          // 1,600,000
    // total ~20.2 MB

    hipMemsetAsync(hist, 0, N_NODES * sizeof(int), stream);
    k_gemm<<<3125, 256, 0, stream>>>(feat, W, att_w, Wh, el, er);
    k_hist<<<(N_EDGES + 255) / 256, 256, 0, stream>>>(dst, hist);
    k_scan<<<1, 1024, 0, stream>>>(hist, offs, cursor);
    k_scatter<<<(N_EDGES + 255) / 256, 256, 0, stream>>>(src, dst, cursor, csr_src);
    k_aggr<<<(N_NODES * 64 + 255) / 256, 256, 0, stream>>>(offs, csr_src, el, er, Wh, bias, out);
}

// Round 3
// 328.659 us; speedup vs baseline: 2.0749x; 1.7271x over previous
//
#include <hip/hip_runtime.h>
#include <math.h>

#define N_NODES 50000
#define N_EDGES 1600000
#define IN_F 256
#define OUT_F 64

typedef short short8 __attribute__((ext_vector_type(8)));
typedef float f32x4 __attribute__((ext_vector_type(4)));

__device__ __forceinline__ unsigned short f2bf(float f) {
    unsigned u = __float_as_uint(f);
    unsigned r = (u + 0x7FFFu + ((u >> 16) & 1u)) >> 16;  // RNE
    return (unsigned short)r;
}

// ---------------- K1: Wh = feature @ W^T via bf16 MFMA, fused el/er -------
// Block 256 (4 waves). Each wave: 32 rows x 64 cols. W staged in LDS in
// MFMA-fragment order (lane-contiguous 16B chunks -> conflict-free).
__global__ __launch_bounds__(256) void k_gemm(const float* __restrict__ feat,
                                              const float* __restrict__ W,
                                              const float* __restrict__ att_w,
                                              float* __restrict__ Wh,
                                              float* __restrict__ el,
                                              float* __restrict__ er) {
    __shared__ unsigned short wlds[16384];  // 32 KB, fragment-ordered bf16 W
    const int tid = threadIdx.x;

    // stage W: chunk c = (ct*8+kt)*64 + l holds W[col][kb..kb+7] as bf16,
    // col = ct*16 + (l&15), kb = kt*32 + 8*(l>>4)
    #pragma unroll
    for (int i = 0; i < 8; ++i) {
        int c = tid + 256 * i;
        int ct = c >> 9, kt = (c >> 6) & 7, cl = c & 63;
        int col = ct * 16 + (cl & 15);
        int kb = kt * 32 + 8 * (cl >> 4);
        const float* p = W + col * 256 + kb;
        float4 x = *(const float4*)p;
        float4 y = *(const float4*)(p + 4);
        short8 v;
        v[0] = f2bf(x.x); v[1] = f2bf(x.y); v[2] = f2bf(x.z); v[3] = f2bf(x.w);
        v[4] = f2bf(y.x); v[5] = f2bf(y.y); v[6] = f2bf(y.z); v[7] = f2bf(y.w);
        *(short8*)(&wlds[c * 8]) = v;
    }
    __syncthreads();

    const int l = tid & 63, w = tid >> 6;
    const int l15 = l & 15, lg = l >> 4;
    const int wbase = blockIdx.x * 128 + w * 32;

    f32x4 acc[2][4];
    #pragma unroll
    for (int rt = 0; rt < 2; ++rt)
        #pragma unroll
        for (int ct = 0; ct < 4; ++ct)
            acc[rt][ct] = (f32x4){0.f, 0.f, 0.f, 0.f};

    #pragma unroll
    for (int kt = 0; kt < 8; ++kt) {
        short8 af[2];
        #pragma unroll
        for (int rt = 0; rt < 2; ++rt) {
            int ar = wbase + rt * 16 + l15;
            if (ar > N_NODES - 1) ar = N_NODES - 1;
            const float* p = feat + (size_t)ar * IN_F + kt * 32 + 8 * lg;
            float4 x = *(const float4*)p;
            float4 y = *(const float4*)(p + 4);
            short8 v;
            v[0] = f2bf(x.x); v[1] = f2bf(x.y); v[2] = f2bf(x.z); v[3] = f2bf(x.w);
            v[4] = f2bf(y.x); v[5] = f2bf(y.y); v[6] = f2bf(y.z); v[7] = f2bf(y.w);
            af[rt] = v;
        }
        #pragma unroll
        for (int ct = 0; ct < 4; ++ct) {
            short8 bf = *(const short8*)(&wlds[((ct * 8 + kt) * 64 + l) * 8]);
            #pragma unroll
            for (int rt = 0; rt < 2; ++rt)
                acc[rt][ct] = __builtin_amdgcn_mfma_f32_16x16x32_bf16(af[rt], bf, acc[rt][ct], 0, 0, 0);
        }
    }

    float asrc[4], adst[4];
    #pragma unroll
    for (int ct = 0; ct < 4; ++ct) {
        asrc[ct] = att_w[ct * 16 + l15];
        adst[ct] = att_w[64 + ct * 16 + l15];
    }

    #pragma unroll
    for (int rt = 0; rt < 2; ++rt) {
        #pragma unroll
        for (int j = 0; j < 4; ++j) {
            int row = wbase + rt * 16 + lg * 4 + j;
            float vs = 0.f, vd = 0.f;
            #pragma unroll
            for (int ct = 0; ct < 4; ++ct) {
                float v = acc[rt][ct][j];
                vs += v * asrc[ct];
                vd += v * adst[ct];
                if (row < N_NODES) Wh[(size_t)row * OUT_F + ct * 16 + l15] = v;
            }
            vs += __shfl_xor(vs, 1); vd += __shfl_xor(vd, 1);
            vs += __shfl_xor(vs, 2); vd += __shfl_xor(vd, 2);
            vs += __shfl_xor(vs, 4); vd += __shfl_xor(vd, 4);
            vs += __shfl_xor(vs, 8); vd += __shfl_xor(vd, 8);
            if (l15 == 0 && row < N_NODES) { el[row] = vs; er[row] = vd; }
        }
    }
}

// ---------------- K2: histogram of dst ----------------
__global__ __launch_bounds__(256) void k_hist(const int* __restrict__ dst,
                                              int* __restrict__ hist) {
    int i = blockIdx.x * 256 + threadIdx.x;
    if (i >= N_EDGES) return;
    atomicAdd(&hist[dst[i]], 1);
}

// ---------------- K3a/b/c: two-level exclusive scan over 50000 ----------
#define SCAN_BLOCKS 196
__global__ __launch_bounds__(256) void k_scan1(const int* __restrict__ hist,
                                               int* __restrict__ blockSums) {
    __shared__ int s[256];
    int t = threadIdx.x;
    int i = blockIdx.x * 256 + t;
    int v = (i < N_NODES) ? hist[i] : 0;
    s[t] = v;
    __syncthreads();
    for (int d = 1; d < 256; d <<= 1) {
        int x = (t >= d) ? s[t - d] : 0;
        __syncthreads();
        s[t] += x;
        __syncthreads();
    }
    if (t == 255) blockSums[blockIdx.x] = s[255];
}

__global__ __launch_bounds__(256) void k_scan2(int* __restrict__ blockSums,
                                               int* __restrict__ blockBase) {
    __shared__ int s[256];
    int t = threadIdx.x;
    int v = (t < SCAN_BLOCKS) ? blockSums[t] : 0;
    s[t] = v;
    __syncthreads();
    for (int d = 1; d < 256; d <<= 1) {
        int x = (t >= d) ? s[t - d] : 0;
        __syncthreads();
        s[t] += x;
        __syncthreads();
    }
    if (t < SCAN_BLOCKS) blockBase[t] = s[t] - v;  // exclusive
}

__global__ __launch_bounds__(256) void k_scan3(const int* __restrict__ hist,
                                               const int* __restrict__ blockBase,
                                               int* __restrict__ offs,
                                               int* __restrict__ cursor) {
    __shared__ int s[256];
    int t = threadIdx.x;
    int i = blockIdx.x * 256 + t;
    int v = (i < N_NODES) ? hist[i] : 0;
    s[t] = v;
    __syncthreads();
    for (int d = 1; d < 256; d <<= 1) {
        int x = (t >= d) ? s[t - d] : 0;
        __syncthreads();
        s[t] += x;
        __syncthreads();
    }
    int base = blockBase[blockIdx.x];
    int excl = base + s[t] - v;
    if (i < N_NODES) { offs[i] = excl; cursor[i] = excl; }
    if (i == N_NODES - 1) offs[N_NODES] = excl + v;
}

// ---------------- K4: scatter src into CSR order ----------------
__global__ __launch_bounds__(256) void k_scatter(const int* __restrict__ src,
                                                 const int* __restrict__ dst,
                                                 int* __restrict__ cursor,
                                                 int* __restrict__ csr_src) {
    int i = blockIdx.x * 256 + threadIdx.x;
    if (i >= N_EDGES) return;
    int d = dst[i];
    int idx = atomicAdd(&cursor[d], 1);
    csr_src[idx] = src[i];
}

// ---------------- K5: per-node gather + softmax + aggregate + epilogue ---
__global__ __launch_bounds__(256) void k_aggr(const int* __restrict__ offs,
                                              const int* __restrict__ csr_src,
                                              const float* __restrict__ el,
                                              const float* __restrict__ er,
                                              const float* __restrict__ Wh,
                                              const float* __restrict__ bias,
                                              float* __restrict__ out) {
    int node = (blockIdx.x * 256 + threadIdx.x) >> 6;
    int lane = threadIdx.x & 63;
    if (node >= N_NODES) return;
    int beg = offs[node], end = offs[node + 1];
    float er_n = er[node];

    float m = -1e30f;
    for (int j = beg + lane; j < end; j += 64) {
        float e = el[csr_src[j]] + er_n;
        e = (e > 0.f) ? e : 0.2f * e;
        m = fmaxf(m, e);
    }
    #pragma unroll
    for (int off = 32; off; off >>= 1) m = fmaxf(m, __shfl_xor(m, off));

    float acc = 0.f, den = 0.f;
    for (int j0 = beg; j0 < end; j0 += 64) {
        int j = j0 + lane;
        float p = 0.f;
        int s = 0;
        if (j < end) {
            s = csr_src[j];
            float e = el[s] + er_n;
            e = (e > 0.f) ? e : 0.2f * e;
            p = __expf(e - m);
        }
        den += p;
        int cnt = end - j0; if (cnt > 64) cnt = 64;
        #pragma unroll 4
        for (int k = 0; k < cnt; ++k) {
            float pk = __shfl(p, k);
            int   sk = __shfl(s, k);
            acc += pk * Wh[(size_t)sk * OUT_F + lane];
        }
    }
    #pragma unroll
    for (int off = 32; off; off >>= 1) den += __shfl_xor(den, off);

    float h = (end > beg) ? (acc / den) : 0.f;
    h += Wh[(size_t)node * OUT_F + lane] + bias[lane];
    out[(size_t)node * OUT_F + lane] = (h > 0.f) ? h : expm1f(h);
}

extern "C" void kernel_launch(void* const* d_in, const int* in_sizes, int n_in,
                              void* d_out, int out_size, void* d_ws, size_t ws_size,
                              hipStream_t stream) {
    const float* feat  = (const float*)d_in[0];
    const float* W     = (const float*)d_in[1];
    const float* att_w = (const float*)d_in[2];
    const float* bias  = (const float*)d_in[3];
    const int*   src   = (const int*)d_in[4];
    const int*   dst   = (const int*)d_in[5];
    float* out = (float*)d_out;

    // workspace layout (4-byte words)
    float* Wh        = (float*)d_ws;            // 3,200,000
    float* el        = Wh + 3200000;            // 50,048
    float* er        = el + 50048;              // 50,048
    int*   hist      = (int*)(er + 50048);      // 50,048
    int*   offs      = hist + 50048;            // 50,064 (needs 50001)
    int*   cursor    = offs + 50064;            // 50,048
    int*   csr_src   = cursor + 50048;          // 1,600,000
    int*   blockSums = csr_src + 1600000;       // 256
    int*   blockBase = blockSums + 256;         // 256

    hipMemsetAsync(hist, 0, N_NODES * sizeof(int), stream);
    k_gemm<<<391, 256, 0, stream>>>(feat, W, att_w, Wh, el, er);
    k_hist<<<(N_EDGES + 255) / 256, 256, 0, stream>>>(dst, hist);
    k_scan1<<<SCAN_BLOCKS, 256, 0, stream>>>(hist, blockSums);
    k_scan2<<<1, 256, 0, stream>>>(blockSums, blockBase);
    k_scan3<<<SCAN_BLOCKS, 256, 0, stream>>>(hist, blockBase, offs, cursor);
    k_scatter<<<(N_EDGES + 255) / 256, 256, 0, stream>>>(src, dst, cursor, csr_src);
    k_aggr<<<(N_NODES * 64 + 255) / 256, 256, 0, stream>>>(offs, csr_src, el, er, Wh, bias, out);
}

// Round 4
// 162.914 us; speedup vs baseline: 4.1858x; 2.0174x over previous
//
#include <hip/hip_runtime.h>
#include <hip/hip_bf16.h>
#include <math.h>

#define N_NODES 50000
#define N_EDGES 1600000
#define IN_F 256
#define OUT_F 64

#define NBUCKETS 196        // ceil(50000/256), bucket = dst >> 8
#define CAP 9216            // per-bucket region capacity (mean 8192, +11 sigma)
#define BK_BLOCKS 391       // level-1 blocks, 4096 edges each
#define EPB 4096

typedef short short8 __attribute__((ext_vector_type(8)));
typedef float f32x4 __attribute__((ext_vector_type(4)));

__device__ __forceinline__ unsigned short f2bf(float f) {
    union { __hip_bfloat16 h; unsigned short u; } v;
    v.h = __float2bfloat16(f);
    return v.u;
}
__device__ __forceinline__ float bf2f(unsigned short u) {
    return __uint_as_float((unsigned)u << 16);
}

// ---------------- K1: Wh = feature @ W^T via bf16 MFMA, fused el/er -------
// Block 256 (4 waves). Each wave: 32 rows x 64 cols. W staged in LDS in
// MFMA-fragment order (lane-contiguous 16B chunks -> conflict-free).
// Wh stored as bf16 (halves write traffic + halves k_aggr gather bytes).
__global__ __launch_bounds__(256) void k_gemm(const float* __restrict__ feat,
                                              const float* __restrict__ W,
                                              const float* __restrict__ att_w,
                                              unsigned short* __restrict__ whb,
                                              float* __restrict__ el,
                                              float* __restrict__ er) {
    __shared__ unsigned short wlds[16384];  // 32 KB, fragment-ordered bf16 W
    const int tid = threadIdx.x;

    #pragma unroll
    for (int i = 0; i < 8; ++i) {
        int c = tid + 256 * i;
        int ct = c >> 9, kt = (c >> 6) & 7, cl = c & 63;
        int col = ct * 16 + (cl & 15);
        int kb = kt * 32 + 8 * (cl >> 4);
        const float* p = W + col * 256 + kb;
        float4 x = *(const float4*)p;
        float4 y = *(const float4*)(p + 4);
        short8 v;
        v[0] = f2bf(x.x); v[1] = f2bf(x.y); v[2] = f2bf(x.z); v[3] = f2bf(x.w);
        v[4] = f2bf(y.x); v[5] = f2bf(y.y); v[6] = f2bf(y.z); v[7] = f2bf(y.w);
        *(short8*)(&wlds[c * 8]) = v;
    }
    __syncthreads();

    const int l = tid & 63, w = tid >> 6;
    const int l15 = l & 15, lg = l >> 4;
    const int wbase = blockIdx.x * 128 + w * 32;

    f32x4 acc[2][4];
    #pragma unroll
    for (int rt = 0; rt < 2; ++rt)
        #pragma unroll
        for (int ct = 0; ct < 4; ++ct)
            acc[rt][ct] = (f32x4){0.f, 0.f, 0.f, 0.f};

    #pragma unroll
    for (int kt = 0; kt < 8; ++kt) {
        short8 af[2];
        #pragma unroll
        for (int rt = 0; rt < 2; ++rt) {
            int ar = wbase + rt * 16 + l15;
            if (ar > N_NODES - 1) ar = N_NODES - 1;
            const float* p = feat + (size_t)ar * IN_F + kt * 32 + 8 * lg;
            float4 x = *(const float4*)p;
            float4 y = *(const float4*)(p + 4);
            short8 v;
            v[0] = f2bf(x.x); v[1] = f2bf(x.y); v[2] = f2bf(x.z); v[3] = f2bf(x.w);
            v[4] = f2bf(y.x); v[5] = f2bf(y.y); v[6] = f2bf(y.z); v[7] = f2bf(y.w);
            af[rt] = v;
        }
        #pragma unroll
        for (int ct = 0; ct < 4; ++ct) {
            short8 bf = *(const short8*)(&wlds[((ct * 8 + kt) * 64 + l) * 8]);
            #pragma unroll
            for (int rt = 0; rt < 2; ++rt)
                acc[rt][ct] = __builtin_amdgcn_mfma_f32_16x16x32_bf16(af[rt], bf, acc[rt][ct], 0, 0, 0);
        }
    }

    float asrc[4], adst[4];
    #pragma unroll
    for (int ct = 0; ct < 4; ++ct) {
        asrc[ct] = att_w[ct * 16 + l15];
        adst[ct] = att_w[64 + ct * 16 + l15];
    }

    #pragma unroll
    for (int rt = 0; rt < 2; ++rt) {
        #pragma unroll
        for (int j = 0; j < 4; ++j) {
            int row = wbase + rt * 16 + lg * 4 + j;
            float vs = 0.f, vd = 0.f;
            #pragma unroll
            for (int ct = 0; ct < 4; ++ct) {
                float v = acc[rt][ct][j];
                vs += v * asrc[ct];
                vd += v * adst[ct];
                if (row < N_NODES) whb[(size_t)row * OUT_F + ct * 16 + l15] = f2bf(v);
            }
            vs += __shfl_xor(vs, 1); vd += __shfl_xor(vd, 1);
            vs += __shfl_xor(vs, 2); vd += __shfl_xor(vd, 2);
            vs += __shfl_xor(vs, 4); vd += __shfl_xor(vd, 4);
            vs += __shfl_xor(vs, 8); vd += __shfl_xor(vd, 8);
            if (l15 == 0 && row < N_NODES) { el[row] = vs; er[row] = vd; }
        }
    }
}

// ---------------- K0: init bucket cursors ----------------
__global__ __launch_bounds__(256) void k_initcur(int* __restrict__ cursor) {
    int t = threadIdx.x;
    if (t < NBUCKETS) cursor[t] = t * CAP;
}

// ---------------- K2: level-1 bucket scatter (bucket = dst>>8) -----------
// Per block: LDS hist over its 4096 edges, one global atomic reservation
// per non-empty bucket, then scatter (src,dst) pairs into block-contiguous
// runs inside each bucket's region.
__global__ __launch_bounds__(256) void k_bucket(const int* __restrict__ src,
                                                const int* __restrict__ dst,
                                                int* __restrict__ cursor,
                                                uint2* __restrict__ pairs) {
    __shared__ int lhist[NBUCKETS];
    __shared__ int lcur[NBUCKETS];
    const int tid = threadIdx.x;
    const int beg = blockIdx.x * EPB;
    int end = beg + EPB; if (end > N_EDGES) end = N_EDGES;

    if (tid < NBUCKETS) lhist[tid] = 0;
    __syncthreads();
    for (int i = beg + tid; i < end; i += 256)
        atomicAdd(&lhist[dst[i] >> 8], 1);
    __syncthreads();
    if (tid < NBUCKETS) {
        int c = lhist[tid];
        lcur[tid] = c ? atomicAdd(&cursor[tid], c) : 0;
    }
    __syncthreads();
    for (int i = beg + tid; i < end; i += 256) {
        int d = dst[i];
        int pos = atomicAdd(&lcur[d >> 8], 1);
        pairs[pos] = make_uint2((unsigned)src[i], (unsigned)d);
    }
}

// ---------------- K3: level-2 CSR build (one block per bucket) -----------
// Counts per-node (LDS), scans (LDS), writes offs/oend, scatters src into
// the block-owned contiguous csr region.
__global__ __launch_bounds__(256) void k_build(const int* __restrict__ cursor,
                                               const uint2* __restrict__ pairs,
                                               int* __restrict__ offs,
                                               int* __restrict__ oend,
                                               int* __restrict__ csr_src) {
    __shared__ int lcnt[256];
    __shared__ int s[256];
    __shared__ int lcur[256];
    const int b = blockIdx.x;
    const int t = threadIdx.x;
    const int ebeg = b * CAP;
    const int eend = cursor[b];

    lcnt[t] = 0;
    __syncthreads();
    for (int i = ebeg + t; i < eend; i += 256)
        atomicAdd(&lcnt[pairs[i].y & 255], 1);
    __syncthreads();

    // inclusive scan over 256
    s[t] = lcnt[t];
    __syncthreads();
    for (int d = 1; d < 256; d <<= 1) {
        int v = (t >= d) ? s[t - d] : 0;
        __syncthreads();
        s[t] += v;
        __syncthreads();
    }
    int base = ebeg + s[t] - lcnt[t];  // csr region shares bucket layout
    lcur[t] = base;
    int node = b * 256 + t;
    if (node < N_NODES) { offs[node] = base; oend[node] = base + lcnt[t]; }
    __syncthreads();

    for (int i = ebeg + t; i < eend; i += 256) {
        uint2 e = pairs[i];
        int pos = atomicAdd(&lcur[e.y & 255], 1);
        csr_src[pos] = (int)e.x;
    }
}

// ---------------- K4: per-node gather + softmax + aggregate + epilogue ---
// No segment-max pass: |e| <= ~12 so exp(e) is safe in fp32 and alpha is
// mathematically identical to the max-subtracted form.
__global__ __launch_bounds__(256) void k_aggr(const int* __restrict__ offs,
                                              const int* __restrict__ oend,
                                              const int* __restrict__ csr_src,
                                              const float* __restrict__ el,
                                              const float* __restrict__ er,
                                              const unsigned short* __restrict__ whb,
                                              const float* __restrict__ bias,
                                              float* __restrict__ out) {
    int node = (blockIdx.x * 256 + threadIdx.x) >> 6;
    int lane = threadIdx.x & 63;
    if (node >= N_NODES) return;
    int beg = offs[node], end = oend[node];
    float er_n = er[node];

    float acc = 0.f, den = 0.f;
    for (int j0 = beg; j0 < end; j0 += 64) {
        int j = j0 + lane;
        float p = 0.f;
        int s = 0;
        if (j < end) {
            s = csr_src[j];
            float e = el[s] + er_n;
            e = (e > 0.f) ? e : 0.2f * e;
            p = __expf(e);
        }
        den += p;
        int cnt = end - j0; if (cnt > 64) cnt = 64;
        #pragma unroll 4
        for (int k = 0; k < cnt; ++k) {
            float pk = __shfl(p, k);
            int   sk = __shfl(s, k);
            acc += pk * bf2f(whb[(size_t)sk * OUT_F + lane]);
        }
    }
    #pragma unroll
    for (int off = 32; off; off >>= 1) den += __shfl_xor(den, off);

    float h = (end > beg) ? (acc / den) : 0.f;
    h += bf2f(whb[(size_t)node * OUT_F + lane]) + bias[lane];
    out[(size_t)node * OUT_F + lane] = (h > 0.f) ? h : expm1f(h);
}

extern "C" void kernel_launch(void* const* d_in, const int* in_sizes, int n_in,
                              void* d_out, int out_size, void* d_ws, size_t ws_size,
                              hipStream_t stream) {
    const float* feat  = (const float*)d_in[0];
    const float* W     = (const float*)d_in[1];
    const float* att_w = (const float*)d_in[2];
    const float* bias  = (const float*)d_in[3];
    const int*   src   = (const int*)d_in[4];
    const int*   dst   = (const int*)d_in[5];
    float* out = (float*)d_out;

    // workspace layout (4-byte words)
    unsigned short* whb = (unsigned short*)d_ws;       // 3,200,000 bf16 = 1,600,000 words
    float* el      = (float*)d_ws + 1600000;           // 50,048
    float* er      = el + 50048;                       // 50,048
    int*   offs    = (int*)(er + 50048);               // 50,048
    int*   oend    = offs + 50048;                     // 50,048
    int*   cursor  = oend + 50048;                     // 256
    uint2* pairs   = (uint2*)(cursor + 256);           // 196*9216 uint2 = 3,612,672 words
    int*   csr_src = (int*)(pairs + NBUCKETS * CAP);   // 1,806,336 words
    // total ~28.9 MB

    k_initcur<<<1, 256, 0, stream>>>(cursor);
    k_gemm<<<391, 256, 0, stream>>>(feat, W, att_w, whb, el, er);
    k_bucket<<<BK_BLOCKS, 256, 0, stream>>>(src, dst, cursor, pairs);
    k_build<<<NBUCKETS, 256, 0, stream>>>(cursor, pairs, offs, oend, csr_src);
    k_aggr<<<(N_NODES * 64 + 255) / 256, 256, 0, stream>>>(offs, oend, csr_src, el, er, whb, bias, out);
}

// Round 5
// 106.942 us; speedup vs baseline: 6.3766x; 1.5234x over previous
//
#include <hip/hip_runtime.h>
#include <hip/hip_bf16.h>
#include <math.h>

#define N_NODES 50000
#define N_EDGES 1600000
#define IN_F 256
#define OUT_F 64

#define NBUCKETS 196        // ceil(50000/256), bucket = dst >> 8
#define CAP 9216            // per-bucket region capacity (mean 8192, +11 sigma)
#define BK_BLOCKS 391       // level-1 blocks, 4096 edges each
#define EPB 4096

typedef short short8 __attribute__((ext_vector_type(8)));
typedef float f32x4 __attribute__((ext_vector_type(4)));

__device__ __forceinline__ unsigned short f2bf(float f) {
    union { __hip_bfloat16 h; unsigned short u; } v;
    v.h = __float2bfloat16(f);
    return v.u;
}
__device__ __forceinline__ float bf2f(unsigned short u) {
    return __uint_as_float((unsigned)u << 16);
}

// ---------------- K1: Wh = feature @ W^T via bf16 MFMA, fused el/er -------
// Block 256 (4 waves). Each wave: 32 rows x 64 cols. W staged in LDS in
// MFMA-fragment order (lane-contiguous 16B chunks -> conflict-free).
// Wh stored as bf16. Block 0 also initializes the bucket cursors.
__global__ __launch_bounds__(256) void k_gemm(const float* __restrict__ feat,
                                              const float* __restrict__ W,
                                              const float* __restrict__ att_w,
                                              unsigned short* __restrict__ whb,
                                              float* __restrict__ el,
                                              float* __restrict__ er,
                                              int* __restrict__ cursor) {
    __shared__ unsigned short wlds[16384];  // 32 KB, fragment-ordered bf16 W
    const int tid = threadIdx.x;

    if (blockIdx.x == 0 && tid < NBUCKETS) cursor[tid] = tid * CAP;

    #pragma unroll
    for (int i = 0; i < 8; ++i) {
        int c = tid + 256 * i;
        int ct = c >> 9, kt = (c >> 6) & 7, cl = c & 63;
        int col = ct * 16 + (cl & 15);
        int kb = kt * 32 + 8 * (cl >> 4);
        const float* p = W + col * 256 + kb;
        float4 x = *(const float4*)p;
        float4 y = *(const float4*)(p + 4);
        short8 v;
        v[0] = f2bf(x.x); v[1] = f2bf(x.y); v[2] = f2bf(x.z); v[3] = f2bf(x.w);
        v[4] = f2bf(y.x); v[5] = f2bf(y.y); v[6] = f2bf(y.z); v[7] = f2bf(y.w);
        *(short8*)(&wlds[c * 8]) = v;
    }
    __syncthreads();

    const int l = tid & 63, w = tid >> 6;
    const int l15 = l & 15, lg = l >> 4;
    const int wbase = blockIdx.x * 128 + w * 32;

    f32x4 acc[2][4];
    #pragma unroll
    for (int rt = 0; rt < 2; ++rt)
        #pragma unroll
        for (int ct = 0; ct < 4; ++ct)
            acc[rt][ct] = (f32x4){0.f, 0.f, 0.f, 0.f};

    #pragma unroll
    for (int kt = 0; kt < 8; ++kt) {
        short8 af[2];
        #pragma unroll
        for (int rt = 0; rt < 2; ++rt) {
            int ar = wbase + rt * 16 + l15;
            if (ar > N_NODES - 1) ar = N_NODES - 1;
            const float* p = feat + (size_t)ar * IN_F + kt * 32 + 8 * lg;
            float4 x = *(const float4*)p;
            float4 y = *(const float4*)(p + 4);
            short8 v;
            v[0] = f2bf(x.x); v[1] = f2bf(x.y); v[2] = f2bf(x.z); v[3] = f2bf(x.w);
            v[4] = f2bf(y.x); v[5] = f2bf(y.y); v[6] = f2bf(y.z); v[7] = f2bf(y.w);
            af[rt] = v;
        }
        #pragma unroll
        for (int ct = 0; ct < 4; ++ct) {
            short8 bf = *(const short8*)(&wlds[((ct * 8 + kt) * 64 + l) * 8]);
            #pragma unroll
            for (int rt = 0; rt < 2; ++rt)
                acc[rt][ct] = __builtin_amdgcn_mfma_f32_16x16x32_bf16(af[rt], bf, acc[rt][ct], 0, 0, 0);
        }
    }

    float asrc[4], adst[4];
    #pragma unroll
    for (int ct = 0; ct < 4; ++ct) {
        asrc[ct] = att_w[ct * 16 + l15];
        adst[ct] = att_w[64 + ct * 16 + l15];
    }

    #pragma unroll
    for (int rt = 0; rt < 2; ++rt) {
        #pragma unroll
        for (int j = 0; j < 4; ++j) {
            int row = wbase + rt * 16 + lg * 4 + j;
            float vs = 0.f, vd = 0.f;
            #pragma unroll
            for (int ct = 0; ct < 4; ++ct) {
                float v = acc[rt][ct][j];
                vs += v * asrc[ct];
                vd += v * adst[ct];
                if (row < N_NODES) whb[(size_t)row * OUT_F + ct * 16 + l15] = f2bf(v);
            }
            vs += __shfl_xor(vs, 1); vd += __shfl_xor(vd, 1);
            vs += __shfl_xor(vs, 2); vd += __shfl_xor(vd, 2);
            vs += __shfl_xor(vs, 4); vd += __shfl_xor(vd, 4);
            vs += __shfl_xor(vs, 8); vd += __shfl_xor(vd, 8);
            if (l15 == 0 && row < N_NODES) { el[row] = vs; er[row] = vd; }
        }
    }
}

// ---------------- K2: level-1 bucket scatter (bucket = dst>>8) -----------
// Packed pair: bits 0-15 = src (< 65536), bits 16-23 = dst & 255.
__global__ __launch_bounds__(256) void k_bucket(const int* __restrict__ src,
                                                const int* __restrict__ dst,
                                                int* __restrict__ cursor,
                                                unsigned* __restrict__ pairs) {
    __shared__ int lhist[NBUCKETS];
    __shared__ int lcur[NBUCKETS];
    const int tid = threadIdx.x;
    const int beg = blockIdx.x * EPB;
    int end = beg + EPB; if (end > N_EDGES) end = N_EDGES;

    if (tid < NBUCKETS) lhist[tid] = 0;
    __syncthreads();
    for (int i = beg + tid; i < end; i += 256)
        atomicAdd(&lhist[dst[i] >> 8], 1);
    __syncthreads();
    if (tid < NBUCKETS) {
        int c = lhist[tid];
        lcur[tid] = c ? atomicAdd(&cursor[tid], c) : 0;
    }
    __syncthreads();
    for (int i = beg + tid; i < end; i += 256) {
        int d = dst[i];
        int pos = atomicAdd(&lcur[d >> 8], 1);
        pairs[pos] = (unsigned)src[i] | ((unsigned)(d & 255) << 16);
    }
}

// ---------------- K3: level-2 CSR build (one block per bucket) -----------
__global__ __launch_bounds__(256) void k_build(const int* __restrict__ cursor,
                                               const unsigned* __restrict__ pairs,
                                               int* __restrict__ offs,
                                               int* __restrict__ oend,
                                               unsigned short* __restrict__ csr_src) {
    __shared__ int lcnt[256];
    __shared__ int s[256];
    __shared__ int lcur[256];
    const int b = blockIdx.x;
    const int t = threadIdx.x;
    const int ebeg = b * CAP;
    const int eend = cursor[b];

    lcnt[t] = 0;
    __syncthreads();
    for (int i = ebeg + t; i < eend; i += 256)
        atomicAdd(&lcnt[(pairs[i] >> 16) & 255], 1);
    __syncthreads();

    s[t] = lcnt[t];
    __syncthreads();
    for (int d = 1; d < 256; d <<= 1) {
        int v = (t >= d) ? s[t - d] : 0;
        __syncthreads();
        s[t] += v;
        __syncthreads();
    }
    int base = ebeg + s[t] - lcnt[t];  // csr region shares bucket layout
    lcur[t] = base;
    int node = b * 256 + t;
    if (node < N_NODES) { offs[node] = base; oend[node] = base + lcnt[t]; }
    __syncthreads();

    for (int i = ebeg + t; i < eend; i += 256) {
        unsigned e = pairs[i];
        int pos = atomicAdd(&lcur[(e >> 16) & 255], 1);
        csr_src[pos] = (unsigned short)(e & 0xFFFFu);
    }
}

// ---------------- K4: per-node gather + softmax + aggregate + epilogue ---
// Wave per node. lane = (edge-slot es = l>>4, feature-group fg = l&15).
// Inner loop: 4 edges per iteration; each lane loads ushort4 (4 bf16) of
// its slot's Wh row -> one VMEM instr covers 4 rows.
__global__ __launch_bounds__(256) void k_aggr(const int* __restrict__ offs,
                                              const int* __restrict__ oend,
                                              const unsigned short* __restrict__ csr_src,
                                              const float* __restrict__ el,
                                              const float* __restrict__ er,
                                              const unsigned short* __restrict__ whb,
                                              const float* __restrict__ bias,
                                              float* __restrict__ out) {
    int node = (blockIdx.x * 256 + threadIdx.x) >> 6;
    int lane = threadIdx.x & 63;
    if (node >= N_NODES) return;
    const int fg = lane & 15;
    const int es = lane >> 4;
    int beg = offs[node], end = oend[node];
    float er_n = er[node];

    float acc0 = 0.f, acc1 = 0.f, acc2 = 0.f, acc3 = 0.f, den = 0.f;
    for (int j0 = beg; j0 < end; j0 += 64) {
        int j = j0 + lane;
        float p = 0.f;
        int s = 0;
        if (j < end) {
            s = (int)csr_src[j];
            float e = el[s] + er_n;
            e = (e > 0.f) ? e : 0.2f * e;
            p = __expf(e);
        }
        den += p;
        int cnt = end - j0; if (cnt > 64) cnt = 64;
        #pragma unroll 2
        for (int k = 0; k < cnt; k += 4) {
            int idx = k + es;                 // <= 63 always
            float pk = __shfl(p, idx);        // lanes past cnt hold p=0
            int   sk = __shfl(s, idx);
            ushort4 wv = *(const ushort4*)(whb + (size_t)sk * OUT_F + fg * 4);
            acc0 += pk * bf2f(wv.x);
            acc1 += pk * bf2f(wv.y);
            acc2 += pk * bf2f(wv.z);
            acc3 += pk * bf2f(wv.w);
        }
    }
    #pragma unroll
    for (int off = 32; off; off >>= 1) den += __shfl_xor(den, off);
    acc0 += __shfl_xor(acc0, 16); acc0 += __shfl_xor(acc0, 32);
    acc1 += __shfl_xor(acc1, 16); acc1 += __shfl_xor(acc1, 32);
    acc2 += __shfl_xor(acc2, 16); acc2 += __shfl_xor(acc2, 32);
    acc3 += __shfl_xor(acc3, 16); acc3 += __shfl_xor(acc3, 32);

    float inv = (end > beg) ? 1.f / den : 0.f;
    ushort4 wn = *(const ushort4*)(whb + (size_t)node * OUT_F + fg * 4);
    float4 b4 = *(const float4*)(bias + fg * 4);
    float h0 = acc0 * inv + bf2f(wn.x) + b4.x;
    float h1 = acc1 * inv + bf2f(wn.y) + b4.y;
    float h2 = acc2 * inv + bf2f(wn.z) + b4.z;
    float h3 = acc3 * inv + bf2f(wn.w) + b4.w;
    h0 = (h0 > 0.f) ? h0 : expm1f(h0);
    h1 = (h1 > 0.f) ? h1 : expm1f(h1);
    h2 = (h2 > 0.f) ? h2 : expm1f(h2);
    h3 = (h3 > 0.f) ? h3 : expm1f(h3);
    if (es == 0)
        *(float4*)(out + (size_t)node * OUT_F + fg * 4) = make_float4(h0, h1, h2, h3);
}

extern "C" void kernel_launch(void* const* d_in, const int* in_sizes, int n_in,
                              void* d_out, int out_size, void* d_ws, size_t ws_size,
                              hipStream_t stream) {
    const float* feat  = (const float*)d_in[0];
    const float* W     = (const float*)d_in[1];
    const float* att_w = (const float*)d_in[2];
    const float* bias  = (const float*)d_in[3];
    const int*   src   = (const int*)d_in[4];
    const int*   dst   = (const int*)d_in[5];
    float* out = (float*)d_out;

    // workspace layout (4-byte words)
    unsigned short* whb = (unsigned short*)d_ws;        // 3,200,000 bf16 = 1,600,000 words
    float* el      = (float*)d_ws + 1600000;            // 50,048
    float* er      = el + 50048;                        // 50,048
    int*   offs    = (int*)(er + 50048);                // 50,048
    int*   oend    = offs + 50048;                      // 50,048
    int*   cursor  = oend + 50048;                      // 256
    unsigned* pairs = (unsigned*)(cursor + 256);        // 196*9216 = 1,806,336 words
    unsigned short* csr_src = (unsigned short*)(pairs + NBUCKETS * CAP);  // 903,168 words
    // total ~18.4 MB

    k_gemm<<<391, 256, 0, stream>>>(feat, W, att_w, whb, el, er, cursor);
    k_bucket<<<BK_BLOCKS, 256, 0, stream>>>(src, dst, cursor, pairs);
    k_build<<<NBUCKETS, 256, 0, stream>>>(cursor, pairs, offs, oend, csr_src);
    k_aggr<<<(N_NODES * 64 + 255) / 256, 256, 0, stream>>>(offs, oend, csr_src, el, er, whb, bias, out);
}

// Round 6
// 97.804 us; speedup vs baseline: 6.9723x; 1.0934x over previous
//
#include <hip/hip_runtime.h>
#include <hip/hip_bf16.h>
#include <math.h>

#define N_NODES 50000
#define N_EDGES 1600000
#define IN_F 256
#define OUT_F 64

#define NBUCKETS 196        // bucket = dst >> 8
#define CAP 9216            // per-bucket region capacity (mean 8192, +11 sigma)
#define GEMM_BLOCKS 391
#define BK_BLOCKS 391       // level-1 blocks, 4096 edges each
#define EPB 4096

typedef short short8 __attribute__((ext_vector_type(8)));
typedef unsigned short ushort8v __attribute__((ext_vector_type(8)));
typedef float f32x4 __attribute__((ext_vector_type(4)));

__device__ __forceinline__ unsigned short f2bf(float f) {
    union { __hip_bfloat16 h; unsigned short u; } v;
    v.h = __float2bfloat16(f);
    return v.u;
}
__device__ __forceinline__ float bf2f(unsigned short u) {
    return __uint_as_float((unsigned)u << 16);
}

// ---------------- K1: fused [gemm | bucket] ----------------
// Blocks 0..390: Wh = feature @ W^T via bf16 MFMA, fused el/er.
// Blocks 391..781: level-1 bucket scatter of (src, dst&255) by dst>>8.
// cnt[] is pure counts (memset 0 before launch) -> no init ordering hazard.
__global__ __launch_bounds__(256) void k_main(const float* __restrict__ feat,
                                              const float* __restrict__ W,
                                              const float* __restrict__ att_w,
                                              unsigned short* __restrict__ whb,
                                              float* __restrict__ el,
                                              float* __restrict__ er,
                                              const int* __restrict__ src,
                                              const int* __restrict__ dst,
                                              int* __restrict__ cnt,
                                              unsigned* __restrict__ pairs) {
    __shared__ unsigned short wlds[16384];  // 32 KB (gemm); aliased by bucket
    const int tid = threadIdx.x;

    if (blockIdx.x >= GEMM_BLOCKS) {
        // ---- bucket part ----
        int* lhist = (int*)wlds;
        int* lcur  = lhist + 256;
        const int beg = (blockIdx.x - GEMM_BLOCKS) * EPB;
        int end = beg + EPB; if (end > N_EDGES) end = N_EDGES;

        if (tid < NBUCKETS) lhist[tid] = 0;
        __syncthreads();
        for (int i = beg + tid; i < end; i += 256)
            atomicAdd(&lhist[dst[i] >> 8], 1);
        __syncthreads();
        if (tid < NBUCKETS) {
            int c = lhist[tid];
            lcur[tid] = c ? (tid * CAP + atomicAdd(&cnt[tid], c)) : 0;
        }
        __syncthreads();
        for (int i = beg + tid; i < end; i += 256) {
            int d = dst[i];
            int pos = atomicAdd(&lcur[d >> 8], 1);
            pairs[pos] = (unsigned)src[i] | ((unsigned)(d & 255) << 16);
        }
        return;
    }

    // ---- gemm part ----
    #pragma unroll
    for (int i = 0; i < 8; ++i) {
        int c = tid + 256 * i;
        int ct = c >> 9, kt = (c >> 6) & 7, cl = c & 63;
        int col = ct * 16 + (cl & 15);
        int kb = kt * 32 + 8 * (cl >> 4);
        const float* p = W + col * 256 + kb;
        float4 x = *(const float4*)p;
        float4 y = *(const float4*)(p + 4);
        short8 v;
        v[0] = f2bf(x.x); v[1] = f2bf(x.y); v[2] = f2bf(x.z); v[3] = f2bf(x.w);
        v[4] = f2bf(y.x); v[5] = f2bf(y.y); v[6] = f2bf(y.z); v[7] = f2bf(y.w);
        *(short8*)(&wlds[c * 8]) = v;
    }
    __syncthreads();

    const int l = tid & 63, w = tid >> 6;
    const int l15 = l & 15, lg = l >> 4;
    const int wbase = blockIdx.x * 128 + w * 32;

    f32x4 acc[2][4];
    #pragma unroll
    for (int rt = 0; rt < 2; ++rt)
        #pragma unroll
        for (int ct = 0; ct < 4; ++ct)
            acc[rt][ct] = (f32x4){0.f, 0.f, 0.f, 0.f};

    #pragma unroll
    for (int kt = 0; kt < 8; ++kt) {
        short8 af[2];
        #pragma unroll
        for (int rt = 0; rt < 2; ++rt) {
            int ar = wbase + rt * 16 + l15;
            if (ar > N_NODES - 1) ar = N_NODES - 1;
            const float* p = feat + (size_t)ar * IN_F + kt * 32 + 8 * lg;
            float4 x = *(const float4*)p;
            float4 y = *(const float4*)(p + 4);
            short8 v;
            v[0] = f2bf(x.x); v[1] = f2bf(x.y); v[2] = f2bf(x.z); v[3] = f2bf(x.w);
            v[4] = f2bf(y.x); v[5] = f2bf(y.y); v[6] = f2bf(y.z); v[7] = f2bf(y.w);
            af[rt] = v;
        }
        #pragma unroll
        for (int ct = 0; ct < 4; ++ct) {
            short8 bf = *(const short8*)(&wlds[((ct * 8 + kt) * 64 + l) * 8]);
            #pragma unroll
            for (int rt = 0; rt < 2; ++rt)
                acc[rt][ct] = __builtin_amdgcn_mfma_f32_16x16x32_bf16(af[rt], bf, acc[rt][ct], 0, 0, 0);
        }
    }

    float asrc[4], adst[4];
    #pragma unroll
    for (int ct = 0; ct < 4; ++ct) {
        asrc[ct] = att_w[ct * 16 + l15];
        adst[ct] = att_w[64 + ct * 16 + l15];
    }

    #pragma unroll
    for (int rt = 0; rt < 2; ++rt) {
        #pragma unroll
        for (int j = 0; j < 4; ++j) {
            int row = wbase + rt * 16 + lg * 4 + j;
            float vs = 0.f, vd = 0.f;
            #pragma unroll
            for (int ct = 0; ct < 4; ++ct) {
                float v = acc[rt][ct][j];
                vs += v * asrc[ct];
                vd += v * adst[ct];
                if (row < N_NODES) whb[(size_t)row * OUT_F + ct * 16 + l15] = f2bf(v);
            }
            vs += __shfl_xor(vs, 1); vd += __shfl_xor(vd, 1);
            vs += __shfl_xor(vs, 2); vd += __shfl_xor(vd, 2);
            vs += __shfl_xor(vs, 4); vd += __shfl_xor(vd, 4);
            vs += __shfl_xor(vs, 8); vd += __shfl_xor(vd, 8);
            if (l15 == 0 && row < N_NODES) { el[row] = vs; er[row] = vd; }
        }
    }
}

// ---------------- K2: level-2 CSR build + softmax numerator/denominator ---
// One 1024-thread block per bucket. Stages the bucket's pairs in LDS,
// counts+scans per-node, then scatters (src|node8, p) uint2 entries where
// p = exp(leaky(el[src]+er[node])), accumulating denom[node] in LDS.
__global__ __launch_bounds__(1024) void k_build(const int* __restrict__ cnt,
                                                const unsigned* __restrict__ pairs,
                                                const float* __restrict__ el,
                                                const float* __restrict__ er,
                                                int* __restrict__ offs,
                                                int* __restrict__ oend,
                                                float* __restrict__ denom,
                                                uint2* __restrict__ csr8) {
    __shared__ unsigned lpairs[CAP];          // 36 KB
    __shared__ int lcnt[256], ssc[256], lcur[256];
    __shared__ float ler[256], lden[256];
    const int b = blockIdx.x;
    const int t = threadIdx.x;
    const int ebeg = b * CAP;
    const int nE = cnt[b];

    if (t < 256) {
        lcnt[t] = 0; lden[t] = 0.f;
        int node = b * 256 + t;
        ler[t] = (node < N_NODES) ? er[node] : 0.f;
    }
    __syncthreads();
    for (int i = t; i < nE; i += 1024) {
        unsigned v = pairs[ebeg + i];
        lpairs[i] = v;
        atomicAdd(&lcnt[(v >> 16) & 255], 1);
    }
    __syncthreads();
    if (t < 256) ssc[t] = lcnt[t];
    __syncthreads();
    for (int d = 1; d < 256; d <<= 1) {
        int v = (t < 256 && t >= d) ? ssc[t - d] : 0;
        __syncthreads();
        if (t < 256) ssc[t] += v;
        __syncthreads();
    }
    if (t < 256) {
        int base = ssc[t] - lcnt[t];
        lcur[t] = base;
        int node = b * 256 + t;
        if (node < N_NODES) { offs[node] = ebeg + base; oend[node] = ebeg + base + lcnt[t]; }
    }
    __syncthreads();
    for (int i = t; i < nE; i += 1024) {
        unsigned v = lpairs[i];
        int n8 = (v >> 16) & 255;
        int s = v & 0xFFFFu;
        float e = el[s] + ler[n8];
        e = (e > 0.f) ? e : 0.2f * e;
        float p = __expf(e);
        int lpos = atomicAdd(&lcur[n8], 1);
        csr8[ebeg + lpos] = make_uint2(v, __float_as_uint(p));
        atomicAdd(&lden[n8], p);
    }
    __syncthreads();
    if (t < 256) {
        int node = b * 256 + t;
        if (node < N_NODES) denom[node] = lden[t];
    }
}

// ---------------- K3: per-node weighted gather + epilogue ----------------
// Wave per node. lane = (edge-slot es = l>>3, feature-group fg = l&7).
// 8 edges/iteration; each lane loads ushort8 (16 B, dwordx4) of its slot's
// Wh row -> one VMEM instr covers 8 rows. p comes packed with src in csr8.
__global__ __launch_bounds__(256) void k_aggr(const int* __restrict__ offs,
                                              const int* __restrict__ oend,
                                              const uint2* __restrict__ csr8,
                                              const float* __restrict__ denom,
                                              const unsigned short* __restrict__ whb,
                                              const float* __restrict__ bias,
                                              float* __restrict__ out) {
    int node = (blockIdx.x * 256 + threadIdx.x) >> 6;
    int lane = threadIdx.x & 63;
    if (node >= N_NODES) return;
    const int fg = lane & 7;
    const int es = lane >> 3;
    int beg = offs[node], end = oend[node];

    float acc[8] = {0.f, 0.f, 0.f, 0.f, 0.f, 0.f, 0.f, 0.f};
    #pragma unroll 2
    for (int j0 = beg; j0 < end; j0 += 8) {
        int j = j0 + es;
        float p = 0.f;
        int s = 0;
        if (j < end) {
            uint2 e = csr8[j];
            s = (int)(e.x & 0xFFFFu);
            p = __uint_as_float(e.y);
        }
        ushort8v wv = *(const ushort8v*)(whb + (size_t)s * OUT_F + fg * 8);
        #pragma unroll
        for (int i = 0; i < 8; ++i) acc[i] += p * bf2f(wv[i]);
    }
    #pragma unroll
    for (int i = 0; i < 8; ++i) {
        acc[i] += __shfl_xor(acc[i], 8);
        acc[i] += __shfl_xor(acc[i], 16);
        acc[i] += __shfl_xor(acc[i], 32);
    }

    if (es == 0) {
        float inv = (end > beg) ? 1.f / denom[node] : 0.f;
        ushort8v wn = *(const ushort8v*)(whb + (size_t)node * OUT_F + fg * 8);
        float4 b0 = *(const float4*)(bias + fg * 8);
        float4 b1 = *(const float4*)(bias + fg * 8 + 4);
        float h[8];
        h[0] = acc[0] * inv + bf2f(wn[0]) + b0.x;
        h[1] = acc[1] * inv + bf2f(wn[1]) + b0.y;
        h[2] = acc[2] * inv + bf2f(wn[2]) + b0.z;
        h[3] = acc[3] * inv + bf2f(wn[3]) + b0.w;
        h[4] = acc[4] * inv + bf2f(wn[4]) + b1.x;
        h[5] = acc[5] * inv + bf2f(wn[5]) + b1.y;
        h[6] = acc[6] * inv + bf2f(wn[6]) + b1.z;
        h[7] = acc[7] * inv + bf2f(wn[7]) + b1.w;
        #pragma unroll
        for (int i = 0; i < 8; ++i) h[i] = (h[i] > 0.f) ? h[i] : expm1f(h[i]);
        float* op = out + (size_t)node * OUT_F + fg * 8;
        *(float4*)op = make_float4(h[0], h[1], h[2], h[3]);
        *(float4*)(op + 4) = make_float4(h[4], h[5], h[6], h[7]);
    }
}

extern "C" void kernel_launch(void* const* d_in, const int* in_sizes, int n_in,
                              void* d_out, int out_size, void* d_ws, size_t ws_size,
                              hipStream_t stream) {
    const float* feat  = (const float*)d_in[0];
    const float* W     = (const float*)d_in[1];
    const float* att_w = (const float*)d_in[2];
    const float* bias  = (const float*)d_in[3];
    const int*   src   = (const int*)d_in[4];
    const int*   dst   = (const int*)d_in[5];
    float* out = (float*)d_out;

    // workspace layout (4-byte words)
    unsigned short* whb = (unsigned short*)d_ws;        // 1,600,000 words (3.2M bf16)
    float* el      = (float*)d_ws + 1600000;            // 50,048
    float* er      = el + 50048;                        // 50,048
    int*   offs    = (int*)(er + 50048);                // 50,048
    int*   oend    = offs + 50048;                      // 50,048
    float* denom   = (float*)(oend + 50048);            // 50,048
    int*   cnt     = (int*)(denom + 50048);             // 256
    unsigned* pairs = (unsigned*)(cnt + 256);           // 1,806,336 words
    uint2* csr8    = (uint2*)(pairs + NBUCKETS * CAP);  // 3,612,672 words
    // total ~29.1 MB

    hipMemsetAsync(cnt, 0, NBUCKETS * sizeof(int), stream);
    k_main<<<GEMM_BLOCKS + BK_BLOCKS, 256, 0, stream>>>(feat, W, att_w, whb, el, er,
                                                        src, dst, cnt, pairs);
    k_build<<<NBUCKETS, 1024, 0, stream>>>(cnt, pairs, el, er, offs, oend, denom, csr8);
    k_aggr<<<(N_NODES * 64 + 255) / 256, 256, 0, stream>>>(offs, oend, csr8, denom, whb, bias, out);
}

// Round 7
// 95.510 us; speedup vs baseline: 7.1398x; 1.0240x over previous
//
#include <hip/hip_runtime.h>
#include <hip/hip_bf16.h>
#include <math.h>

#define N_NODES 50000
#define N_EDGES 1600000
#define IN_F 256
#define OUT_F 64

#define NBUCKETS 391        // bucket = dst >> 7 (128 nodes each), max idx 390
#define CAP 4736            // per-bucket capacity (mean 4092, ~ +10 sigma)
#define GEMM_BLOCKS 782     // 64 rows each
#define BK_BLOCKS 782       // 2048 edges each
#define EPB 2048

typedef short short8 __attribute__((ext_vector_type(8)));
typedef float f32x4 __attribute__((ext_vector_type(4)));

__device__ __forceinline__ unsigned short f2bf(float f) {
    union { __hip_bfloat16 h; unsigned short u; } v;
    v.h = __float2bfloat16(f);
    return v.u;
}
__device__ __forceinline__ float bf2f(unsigned u) {
    return __uint_as_float(u << 16);
}

// ---------------- K0: prep — W -> fragment-ordered bf16 wfrag; zero cnt ---
// chunk c (0..2047): ct=c>>9, kt=(c>>6)&7, l=c&63 holds
// W[col=ct*16+(l&15)][kb=kt*32+8*(l>>4) .. +8] as short8.
__global__ __launch_bounds__(256) void k_prep(const float* __restrict__ W,
                                              unsigned short* __restrict__ wfrag,
                                              int* __restrict__ cnt) {
    const int tid = threadIdx.x;
    if (blockIdx.x == 0)
        for (int i = tid; i < NBUCKETS; i += 256) cnt[i] = 0;
    int c = blockIdx.x * 256 + tid;
    int ct = c >> 9, kt = (c >> 6) & 7, cl = c & 63;
    int col = ct * 16 + (cl & 15);
    int kb = kt * 32 + 8 * (cl >> 4);
    const float* p = W + col * 256 + kb;
    float4 x = *(const float4*)p;
    float4 y = *(const float4*)(p + 4);
    short8 v;
    v[0] = f2bf(x.x); v[1] = f2bf(x.y); v[2] = f2bf(x.z); v[3] = f2bf(x.w);
    v[4] = f2bf(y.x); v[5] = f2bf(y.y); v[6] = f2bf(y.z); v[7] = f2bf(y.w);
    *(short8*)(wfrag + c * 8) = v;
}

// ---------------- K1: fused [gemm | bucket] ----------------
// Blocks 0..781: 64 rows of Wh = feat @ W^T (bf16 MFMA, no LDS), fused el/er.
// Blocks 782..1563: level-1 bucket scatter of (src, dst&127) by dst>>7.
__global__ __launch_bounds__(256) void k_main(const float* __restrict__ feat,
                                              const unsigned short* __restrict__ wfrag,
                                              const float* __restrict__ att_w,
                                              unsigned short* __restrict__ whb,
                                              float* __restrict__ el,
                                              float* __restrict__ er,
                                              const int* __restrict__ src,
                                              const int* __restrict__ dst,
                                              int* __restrict__ cnt,
                                              unsigned* __restrict__ pairs) {
    const int tid = threadIdx.x;

    if (blockIdx.x >= GEMM_BLOCKS) {
        // ---- bucket part ----
        __shared__ int lhist[NBUCKETS];
        __shared__ int lcur[NBUCKETS];
        const int beg = (blockIdx.x - GEMM_BLOCKS) * EPB;
        int end = beg + EPB; if (end > N_EDGES) end = N_EDGES;
        for (int i = tid; i < NBUCKETS; i += 256) lhist[i] = 0;
        __syncthreads();

        int e0 = beg + tid * 8;
        int n = (e0 < end) ? ((end - e0 < 8) ? (end - e0) : 8) : 0;
        int d[8], s[8];
        if (n == 8) {
            int4 a = *(const int4*)(dst + e0), b = *(const int4*)(dst + e0 + 4);
            int4 c = *(const int4*)(src + e0), q = *(const int4*)(src + e0 + 4);
            d[0]=a.x; d[1]=a.y; d[2]=a.z; d[3]=a.w; d[4]=b.x; d[5]=b.y; d[6]=b.z; d[7]=b.w;
            s[0]=c.x; s[1]=c.y; s[2]=c.z; s[3]=c.w; s[4]=q.x; s[5]=q.y; s[6]=q.z; s[7]=q.w;
        } else {
            #pragma unroll
            for (int j = 0; j < 8; ++j) { d[j] = (j < n) ? dst[e0 + j] : 0; s[j] = (j < n) ? src[e0 + j] : 0; }
        }
        #pragma unroll
        for (int j = 0; j < 8; ++j) if (j < n) atomicAdd(&lhist[d[j] >> 7], 1);
        __syncthreads();
        for (int i = tid; i < NBUCKETS; i += 256) {
            int c = lhist[i];
            lcur[i] = c ? (i * CAP + atomicAdd(&cnt[i], c)) : 0;
        }
        __syncthreads();
        #pragma unroll
        for (int j = 0; j < 8; ++j) if (j < n) {
            int pos = atomicAdd(&lcur[d[j] >> 7], 1);
            pairs[pos] = (unsigned)s[j] | ((unsigned)(d[j] & 127) << 16);
        }
        return;
    }

    // ---- gemm part: wave = 16 rows x 64 cols ----
    const int l = tid & 63, w = tid >> 6;
    const int l15 = l & 15, lg = l >> 4;
    const int wbase = blockIdx.x * 64 + w * 16;
    int ar = wbase + l15; if (ar > N_NODES - 1) ar = N_NODES - 1;
    const float* fbase = feat + (size_t)ar * IN_F + 8 * lg;
    const unsigned short* wfl = wfrag + l * 8;

    f32x4 acc[4];
    #pragma unroll
    for (int ct = 0; ct < 4; ++ct) acc[ct] = (f32x4){0.f, 0.f, 0.f, 0.f};

    float4 fa = *(const float4*)(fbase);
    float4 fb = *(const float4*)(fbase + 4);
    #pragma unroll
    for (int kt = 0; kt < 8; ++kt) {
        float4 na, nb;
        if (kt < 7) {
            na = *(const float4*)(fbase + (kt + 1) * 32);
            nb = *(const float4*)(fbase + (kt + 1) * 32 + 4);
        }
        short8 bf0 = *(const short8*)(wfl + (0 * 8 + kt) * 512);
        short8 bf1 = *(const short8*)(wfl + (1 * 8 + kt) * 512);
        short8 bf2 = *(const short8*)(wfl + (2 * 8 + kt) * 512);
        short8 bf3 = *(const short8*)(wfl + (3 * 8 + kt) * 512);
        short8 af;
        af[0] = f2bf(fa.x); af[1] = f2bf(fa.y); af[2] = f2bf(fa.z); af[3] = f2bf(fa.w);
        af[4] = f2bf(fb.x); af[5] = f2bf(fb.y); af[6] = f2bf(fb.z); af[7] = f2bf(fb.w);
        acc[0] = __builtin_amdgcn_mfma_f32_16x16x32_bf16(af, bf0, acc[0], 0, 0, 0);
        acc[1] = __builtin_amdgcn_mfma_f32_16x16x32_bf16(af, bf1, acc[1], 0, 0, 0);
        acc[2] = __builtin_amdgcn_mfma_f32_16x16x32_bf16(af, bf2, acc[2], 0, 0, 0);
        acc[3] = __builtin_amdgcn_mfma_f32_16x16x32_bf16(af, bf3, acc[3], 0, 0, 0);
        fa = na; fb = nb;
    }

    float asrc[4], adst[4];
    #pragma unroll
    for (int ct = 0; ct < 4; ++ct) {
        asrc[ct] = att_w[ct * 16 + l15];
        adst[ct] = att_w[64 + ct * 16 + l15];
    }
    #pragma unroll
    for (int j = 0; j < 4; ++j) {
        int row = wbase + lg * 4 + j;
        float vs = 0.f, vd = 0.f;
        #pragma unroll
        for (int ct = 0; ct < 4; ++ct) {
            float v = acc[ct][j];
            vs += v * asrc[ct];
            vd += v * adst[ct];
            if (row < N_NODES) whb[(size_t)row * OUT_F + ct * 16 + l15] = f2bf(v);
        }
        vs += __shfl_xor(vs, 1); vd += __shfl_xor(vd, 1);
        vs += __shfl_xor(vs, 2); vd += __shfl_xor(vd, 2);
        vs += __shfl_xor(vs, 4); vd += __shfl_xor(vd, 4);
        vs += __shfl_xor(vs, 8); vd += __shfl_xor(vd, 8);
        if (l15 == 0 && row < N_NODES) { el[row] = vs; er[row] = vd; }
    }
}

// ---------------- K2: level-2 CSR build (one block per bucket) -----------
// csr word = src(16b) | p-as-bf16(16b), p = exp(leaky(el[src]+er[node])).
__global__ __launch_bounds__(1024) void k_build(const int* __restrict__ cnt,
                                                const unsigned* __restrict__ pairs,
                                                const float* __restrict__ el,
                                                const float* __restrict__ er,
                                                int* __restrict__ offs,
                                                int* __restrict__ oend,
                                                unsigned* __restrict__ csr) {
    __shared__ int lcnt[128], ssc[128], lcur[128];
    __shared__ float ler[128];
    const int b = blockIdx.x;
    const int t = threadIdx.x;
    const int ebeg = b * CAP;
    const int nE = cnt[b];

    if (t < 128) {
        lcnt[t] = 0;
        int node = b * 128 + t;
        ler[t] = (node < N_NODES) ? er[node] : 0.f;
    }
    __syncthreads();
    for (int i = t; i < nE; i += 1024)
        atomicAdd(&lcnt[(pairs[ebeg + i] >> 16) & 127], 1);
    __syncthreads();
    if (t < 128) ssc[t] = lcnt[t];
    __syncthreads();
    for (int d = 1; d < 128; d <<= 1) {
        int v = 0;
        if (t < 128 && t >= d) v = ssc[t - d];
        __syncthreads();
        if (t < 128) ssc[t] += v;
        __syncthreads();
    }
    if (t < 128) {
        int base = ssc[t] - lcnt[t];
        lcur[t] = base;
        int node = b * 128 + t;
        if (node < N_NODES) { offs[node] = ebeg + base; oend[node] = ebeg + base + lcnt[t]; }
    }
    __syncthreads();
    for (int i = t; i < nE; i += 1024) {
        unsigned v = pairs[ebeg + i];
        int n7 = (v >> 16) & 127;
        int s = v & 0xFFFFu;
        float e = el[s] + ler[n7];
        e = (e > 0.f) ? e : 0.2f * e;
        float p = __expf(e);
        int pos = atomicAdd(&lcur[n7], 1);
        csr[ebeg + pos] = (unsigned)s | ((unsigned)f2bf(p) << 16);
    }
}

// ---------------- K3: per-node gather — uniform-s scheme ----------------
// Wave per node (node id via readfirstlane -> csr reads are SCALAR loads;
// s, p live in SGPRs). Lane = feature: per edge one coalesced 128B
// global_load_ushort + 1 unpack + 1 FMA + 1 den add. No cross-lane ops.
__global__ __launch_bounds__(256) void k_aggr(const int* __restrict__ offs,
                                              const int* __restrict__ oend,
                                              const unsigned* __restrict__ csr,
                                              const unsigned short* __restrict__ whb,
                                              const float* __restrict__ bias,
                                              float* __restrict__ out) {
    const int wid = __builtin_amdgcn_readfirstlane(threadIdx.x >> 6);
    const int node = blockIdx.x * 4 + wid;
    const int lane = threadIdx.x & 63;
    const int beg = offs[node], end = oend[node];

    float acc = 0.f, den = 0.f;
    #pragma unroll 4
    for (int j = beg; j < end; ++j) {
        unsigned e = csr[j];                       // scalar load (uniform j)
        float p = bf2f(e >> 16);
        unsigned short wv = whb[(size_t)(e & 0xFFFFu) * OUT_F + lane];
        acc = fmaf(p, bf2f((unsigned)wv), acc);
        den += p;
    }
    float inv = (end > beg) ? 1.f / den : 0.f;
    float h = acc * inv + bf2f((unsigned)whb[(size_t)node * OUT_F + lane]) + bias[lane];
    out[(size_t)node * OUT_F + lane] = (h > 0.f) ? h : __expf(h) - 1.f;
}

extern "C" void kernel_launch(void* const* d_in, const int* in_sizes, int n_in,
                              void* d_out, int out_size, void* d_ws, size_t ws_size,
                              hipStream_t stream) {
    const float* feat  = (const float*)d_in[0];
    const float* W     = (const float*)d_in[1];
    const float* att_w = (const float*)d_in[2];
    const float* bias  = (const float*)d_in[3];
    const int*   src   = (const int*)d_in[4];
    const int*   dst   = (const int*)d_in[5];
    float* out = (float*)d_out;

    // workspace layout (4-byte words)
    unsigned short* whb = (unsigned short*)d_ws;          // 1,600,000 words
    unsigned short* wfrag = whb + 3200000;                // 8,192 words (32 KB)
    float* el      = (float*)d_ws + 1600000 + 8192;       // 50,048
    float* er      = el + 50048;                          // 50,048
    int*   offs    = (int*)(er + 50048);                  // 50,048
    int*   oend    = offs + 50048;                        // 50,048
    int*   cnt     = oend + 50048;                        // 512
    unsigned* pairs = (unsigned*)(cnt + 512);             // 391*4736 = 1,851,776 words
    unsigned* csr   = pairs + NBUCKETS * CAP;             // 1,851,776 words
    // total ~22.1 MB

    k_prep<<<8, 256, 0, stream>>>(W, wfrag, cnt);
    k_main<<<GEMM_BLOCKS + BK_BLOCKS, 256, 0, stream>>>(feat, wfrag, att_w, whb, el, er,
                                                        src, dst, cnt, pairs);
    k_build<<<NBUCKETS, 1024, 0, stream>>>(cnt, pairs, el, er, offs, oend, csr);
    k_aggr<<<N_NODES / 4, 256, 0, stream>>>(offs, oend, csr, whb, bias, out);
}

// Round 8
// 91.875 us; speedup vs baseline: 7.4223x; 1.0396x over previous
//
#include <hip/hip_runtime.h>
#include <hip/hip_bf16.h>
#include <math.h>

#define N_NODES 50000
#define N_EDGES 1600000
#define IN_F 256
#define OUT_F 64

#define NBUCKETS 196        // bucket = dst >> 8 (256 nodes each)
#define CAP 10240           // per-bucket capacity (mean 8192 + pad 768 + slack)
#define GEMM_BLOCKS 782     // 64 rows each
#define BK_BLOCKS 391       // 4096 edges each
#define EPB 4096

typedef short short8 __attribute__((ext_vector_type(8)));
typedef float f32x4 __attribute__((ext_vector_type(4)));

__device__ __forceinline__ unsigned short f2bf(float f) {
    union { __hip_bfloat16 h; unsigned short u; } v;
    v.h = __float2bfloat16(f);
    return v.u;
}
__device__ __forceinline__ float bf2f(unsigned u) {
    return __uint_as_float(u << 16);
}

// ---------------- K0: prep — W -> fragment-ordered bf16 wfrag; zero cnt ---
__global__ __launch_bounds__(256) void k_prep(const float* __restrict__ W,
                                              unsigned short* __restrict__ wfrag,
                                              int* __restrict__ cnt) {
    const int tid = threadIdx.x;
    if (blockIdx.x == 0 && tid < NBUCKETS) cnt[tid] = 0;
    int c = blockIdx.x * 256 + tid;
    int ct = c >> 9, kt = (c >> 6) & 7, cl = c & 63;
    int col = ct * 16 + (cl & 15);
    int kb = kt * 32 + 8 * (cl >> 4);
    const float* p = W + col * 256 + kb;
    float4 x = *(const float4*)p;
    float4 y = *(const float4*)(p + 4);
    short8 v;
    v[0] = f2bf(x.x); v[1] = f2bf(x.y); v[2] = f2bf(x.z); v[3] = f2bf(x.w);
    v[4] = f2bf(y.x); v[5] = f2bf(y.y); v[6] = f2bf(y.z); v[7] = f2bf(y.w);
    *(short8*)(wfrag + c * 8) = v;
}

// ---------------- K1: fused [gemm | bucket] ----------------
// Blocks 0..781: 64 rows of Wh = feat @ W^T (bf16 MFMA, no LDS), fused el/er.
// Blocks 782..1172: level-1 bucket scatter of (src, dst&255) by dst>>8.
__global__ __launch_bounds__(256) void k_main(const float* __restrict__ feat,
                                              const unsigned short* __restrict__ wfrag,
                                              const float* __restrict__ att_w,
                                              unsigned short* __restrict__ whb,
                                              float* __restrict__ el,
                                              float* __restrict__ er,
                                              const int* __restrict__ src,
                                              const int* __restrict__ dst,
                                              int* __restrict__ cnt,
                                              unsigned* __restrict__ pairs) {
    const int tid = threadIdx.x;

    if (blockIdx.x >= GEMM_BLOCKS) {
        // ---- bucket part ----
        __shared__ int lhist[NBUCKETS];
        __shared__ int lcur[NBUCKETS];
        const int beg = (blockIdx.x - GEMM_BLOCKS) * EPB;
        int end = beg + EPB; if (end > N_EDGES) end = N_EDGES;
        if (tid < NBUCKETS) lhist[tid] = 0;
        __syncthreads();
        for (int i = beg + tid; i < end; i += 256)
            atomicAdd(&lhist[dst[i] >> 8], 1);
        __syncthreads();
        if (tid < NBUCKETS) {
            int c = lhist[tid];
            lcur[tid] = c ? (tid * CAP + atomicAdd(&cnt[tid], c)) : 0;
        }
        __syncthreads();
        for (int i = beg + tid; i < end; i += 256) {
            int d = dst[i];
            int pos = atomicAdd(&lcur[d >> 8], 1);
            pairs[pos] = (unsigned)src[i] | ((unsigned)(d & 255) << 16);
        }
        return;
    }

    // ---- gemm part: wave = 16 rows x 64 cols ----
    const int l = tid & 63, w = tid >> 6;
    const int l15 = l & 15, lg = l >> 4;
    const int wbase = blockIdx.x * 64 + w * 16;
    int ar = wbase + l15; if (ar > N_NODES - 1) ar = N_NODES - 1;
    const float* fbase = feat + (size_t)ar * IN_F + 8 * lg;
    const unsigned short* wfl = wfrag + l * 8;

    f32x4 acc[4];
    #pragma unroll
    for (int ct = 0; ct < 4; ++ct) acc[ct] = (f32x4){0.f, 0.f, 0.f, 0.f};

    float4 fa = *(const float4*)(fbase);
    float4 fb = *(const float4*)(fbase + 4);
    #pragma unroll
    for (int kt = 0; kt < 8; ++kt) {
        float4 na, nb;
        if (kt < 7) {
            na = *(const float4*)(fbase + (kt + 1) * 32);
            nb = *(const float4*)(fbase + (kt + 1) * 32 + 4);
        }
        short8 bf0 = *(const short8*)(wfl + (0 * 8 + kt) * 512);
        short8 bf1 = *(const short8*)(wfl + (1 * 8 + kt) * 512);
        short8 bf2 = *(const short8*)(wfl + (2 * 8 + kt) * 512);
        short8 bf3 = *(const short8*)(wfl + (3 * 8 + kt) * 512);
        short8 af;
        af[0] = f2bf(fa.x); af[1] = f2bf(fa.y); af[2] = f2bf(fa.z); af[3] = f2bf(fa.w);
        af[4] = f2bf(fb.x); af[5] = f2bf(fb.y); af[6] = f2bf(fb.z); af[7] = f2bf(fb.w);
        acc[0] = __builtin_amdgcn_mfma_f32_16x16x32_bf16(af, bf0, acc[0], 0, 0, 0);
        acc[1] = __builtin_amdgcn_mfma_f32_16x16x32_bf16(af, bf1, acc[1], 0, 0, 0);
        acc[2] = __builtin_amdgcn_mfma_f32_16x16x32_bf16(af, bf2, acc[2], 0, 0, 0);
        acc[3] = __builtin_amdgcn_mfma_f32_16x16x32_bf16(af, bf3, acc[3], 0, 0, 0);
        fa = na; fb = nb;
    }

    float asrc[4], adst[4];
    #pragma unroll
    for (int ct = 0; ct < 4; ++ct) {
        asrc[ct] = att_w[ct * 16 + l15];
        adst[ct] = att_w[64 + ct * 16 + l15];
    }
    #pragma unroll
    for (int j = 0; j < 4; ++j) {
        int row = wbase + lg * 4 + j;
        float vs = 0.f, vd = 0.f;
        #pragma unroll
        for (int ct = 0; ct < 4; ++ct) {
            float v = acc[ct][j];
            vs += v * asrc[ct];
            vd += v * adst[ct];
            if (row < N_NODES) whb[(size_t)row * OUT_F + ct * 16 + l15] = f2bf(v);
        }
        vs += __shfl_xor(vs, 1); vd += __shfl_xor(vd, 1);
        vs += __shfl_xor(vs, 2); vd += __shfl_xor(vd, 2);
        vs += __shfl_xor(vs, 4); vd += __shfl_xor(vd, 4);
        vs += __shfl_xor(vs, 8); vd += __shfl_xor(vd, 8);
        if (l15 == 0 && row < N_NODES) { el[row] = vs; er[row] = vd; }
    }
}

// ---------------- K2: level-2 CSR build (one block per bucket) -----------
// csr word = src(16b) | p-as-bf16(16b), p = exp(leaky(el[src]+er[node])).
// Each node's segment is padded to a multiple of 4 with zero entries
// (p=0, s=0) so k_aggr's loop needs no bounds checks.
__global__ __launch_bounds__(1024) void k_build(const int* __restrict__ cnt,
                                                const unsigned* __restrict__ pairs,
                                                const float* __restrict__ el,
                                                const float* __restrict__ er,
                                                int* __restrict__ offs,
                                                int* __restrict__ oend,
                                                unsigned* __restrict__ csr) {
    __shared__ int lcnt[256], ssc[256], lcur[256];
    __shared__ float ler[256];
    const int b = blockIdx.x;
    const int t = threadIdx.x;
    const int ebeg = b * CAP;
    const int nE = cnt[b];

    if (t < 256) {
        lcnt[t] = 0;
        int node = b * 256 + t;
        ler[t] = (node < N_NODES) ? er[node] : 0.f;
    }
    __syncthreads();
    for (int i = t; i < nE; i += 1024)
        atomicAdd(&lcnt[(pairs[ebeg + i] >> 16) & 255], 1);
    __syncthreads();
    if (t < 256) ssc[t] = (lcnt[t] + 3) & ~3;   // padded count
    __syncthreads();
    for (int d = 1; d < 256; d <<= 1) {
        int v = 0;
        if (t < 256 && t >= d) v = ssc[t - d];
        __syncthreads();
        if (t < 256) ssc[t] += v;
        __syncthreads();
    }
    if (t < 256) {
        int pc = (lcnt[t] + 3) & ~3;
        int base = ssc[t] - pc;               // 4-aligned
        lcur[t] = base;
        int node = b * 256 + t;
        if (node < N_NODES) { offs[node] = ebeg + base; oend[node] = ebeg + base + pc; }
        for (int k = lcnt[t]; k < pc; ++k) csr[ebeg + base + k] = 0;  // pad
    }
    __syncthreads();
    for (int i = t; i < nE; i += 1024) {
        unsigned v = pairs[ebeg + i];
        int n8 = (v >> 16) & 255;
        int s = v & 0xFFFFu;
        float e = el[s] + ler[n8];
        e = (e > 0.f) ? e : 0.2f * e;
        float p = __expf(e);
        int pos = atomicAdd(&lcur[n8], 1);
        csr[ebeg + pos] = (unsigned)s | ((unsigned)f2bf(p) << 16);
    }
}

// ---------------- K3: per-node gather — 4 edges per VMEM ----------------
// Wave per node. lane = (edge-slot es = l>>4, feature-group fg = l&15).
// csr[j+es] is a broadcast 16B load; each lane loads ushort4 (8B) of its
// slot's Wh row -> one wave VMEM covers 4 rows. Segments are 4-padded so
// the loop is branch-free. p unpacks from the lane's own csr word.
__global__ __launch_bounds__(256) void k_aggr(const int* __restrict__ offs,
                                              const int* __restrict__ oend,
                                              const unsigned* __restrict__ csr,
                                              const unsigned short* __restrict__ whb,
                                              const float* __restrict__ bias,
                                              float* __restrict__ out) {
    const int wid = __builtin_amdgcn_readfirstlane(threadIdx.x >> 6);
    const int node = blockIdx.x * 4 + wid;
    const int lane = threadIdx.x & 63;
    const int fg = lane & 15, es = lane >> 4;
    const int beg = offs[node], end = oend[node];

    float acc0 = 0.f, acc1 = 0.f, acc2 = 0.f, acc3 = 0.f, den = 0.f;
    #pragma unroll 2
    for (int j = beg; j < end; j += 4) {
        unsigned e = csr[j + es];
        float p = __uint_as_float(e & 0xFFFF0000u);
        const unsigned short* wp = whb + (size_t)(e & 0xFFFFu) * OUT_F + fg * 4;
        ushort4 wv = *(const ushort4*)wp;
        den += p;
        acc0 = fmaf(p, bf2f((unsigned)wv.x), acc0);
        acc1 = fmaf(p, bf2f((unsigned)wv.y), acc1);
        acc2 = fmaf(p, bf2f((unsigned)wv.z), acc2);
        acc3 = fmaf(p, bf2f((unsigned)wv.w), acc3);
    }
    acc0 += __shfl_xor(acc0, 16); acc0 += __shfl_xor(acc0, 32);
    acc1 += __shfl_xor(acc1, 16); acc1 += __shfl_xor(acc1, 32);
    acc2 += __shfl_xor(acc2, 16); acc2 += __shfl_xor(acc2, 32);
    acc3 += __shfl_xor(acc3, 16); acc3 += __shfl_xor(acc3, 32);
    den  += __shfl_xor(den, 16);  den  += __shfl_xor(den, 32);

    if (es == 0) {
        float inv = (end > beg) ? 1.f / den : 0.f;
        ushort4 wn = *(const ushort4*)(whb + (size_t)node * OUT_F + fg * 4);
        float4 b4 = *(const float4*)(bias + fg * 4);
        float h0 = acc0 * inv + bf2f((unsigned)wn.x) + b4.x;
        float h1 = acc1 * inv + bf2f((unsigned)wn.y) + b4.y;
        float h2 = acc2 * inv + bf2f((unsigned)wn.z) + b4.z;
        float h3 = acc3 * inv + bf2f((unsigned)wn.w) + b4.w;
        h0 = (h0 > 0.f) ? h0 : __expf(h0) - 1.f;
        h1 = (h1 > 0.f) ? h1 : __expf(h1) - 1.f;
        h2 = (h2 > 0.f) ? h2 : __expf(h2) - 1.f;
        h3 = (h3 > 0.f) ? h3 : __expf(h3) - 1.f;
        *(float4*)(out + (size_t)node * OUT_F + fg * 4) = make_float4(h0, h1, h2, h3);
    }
}

extern "C" void kernel_launch(void* const* d_in, const int* in_sizes, int n_in,
                              void* d_out, int out_size, void* d_ws, size_t ws_size,
                              hipStream_t stream) {
    const float* feat  = (const float*)d_in[0];
    const float* W     = (const float*)d_in[1];
    const float* att_w = (const float*)d_in[2];
    const float* bias  = (const float*)d_in[3];
    const int*   src   = (const int*)d_in[4];
    const int*   dst   = (const int*)d_in[5];
    float* out = (float*)d_out;

    // workspace layout (4-byte words)
    unsigned short* whb = (unsigned short*)d_ws;          // 1,600,000 words
    unsigned short* wfrag = whb + 3200000;                // 8,192 words (32 KB)
    float* el      = (float*)d_ws + 1600000 + 8192;       // 50,048
    float* er      = el + 50048;                          // 50,048
    int*   offs    = (int*)(er + 50048);                  // 50,048
    int*   oend    = offs + 50048;                        // 50,048
    int*   cnt     = oend + 50048;                        // 512
    unsigned* pairs = (unsigned*)(cnt + 512);             // 196*10240 = 2,007,040 words
    unsigned* csr   = pairs + NBUCKETS * CAP;             // 2,007,040 words
    // total ~23.5 MB

    k_prep<<<8, 256, 0, stream>>>(W, wfrag, cnt);
    k_main<<<GEMM_BLOCKS + BK_BLOCKS, 256, 0, stream>>>(feat, wfrag, att_w, whb, el, er,
                                                        src, dst, cnt, pairs);
    k_build<<<NBUCKETS, 1024, 0, stream>>>(cnt, pairs, el, er, offs, oend, csr);
    k_aggr<<<N_NODES / 4, 256, 0, stream>>>(offs, oend, csr, whb, bias, out);
}

// Round 9
// 87.151 us; speedup vs baseline: 7.8246x; 1.0542x over previous
//
#include <hip/hip_runtime.h>
#include <hip/hip_bf16.h>
#include <math.h>

#define N_NODES 50000
#define N_EDGES 1600000
#define IN_F 256
#define OUT_F 64

#define NBUCKETS 196        // bucket = dst >> 8 (256 nodes each)
#define CAP 10240           // per-bucket capacity (mean 8192 + pad 768 + slack)
#define GEMM_BLOCKS 782     // 64 rows each
#define BK_BLOCKS 391       // 4096 edges each
#define EPB 4096

typedef short short8 __attribute__((ext_vector_type(8)));
typedef float f32x4 __attribute__((ext_vector_type(4)));

__device__ __forceinline__ unsigned short f2bf(float f) {
    union { __hip_bfloat16 h; unsigned short u; } v;
    v.h = __float2bfloat16(f);
    return v.u;
}
__device__ __forceinline__ float bf2f(unsigned u) {
    return __uint_as_float(u << 16);
}

// ---------------- K0: prep — W -> fragment-ordered bf16 wfrag; zero cnt ---
__global__ __launch_bounds__(256) void k_prep(const float* __restrict__ W,
                                              unsigned short* __restrict__ wfrag,
                                              int* __restrict__ cnt) {
    const int tid = threadIdx.x;
    if (blockIdx.x == 0 && tid < NBUCKETS) cnt[tid] = 0;
    int c = blockIdx.x * 256 + tid;
    int ct = c >> 9, kt = (c >> 6) & 7, cl = c & 63;
    int col = ct * 16 + (cl & 15);
    int kb = kt * 32 + 8 * (cl >> 4);
    const float* p = W + col * 256 + kb;
    float4 x = *(const float4*)p;
    float4 y = *(const float4*)(p + 4);
    short8 v;
    v[0] = f2bf(x.x); v[1] = f2bf(x.y); v[2] = f2bf(x.z); v[3] = f2bf(x.w);
    v[4] = f2bf(y.x); v[5] = f2bf(y.y); v[6] = f2bf(y.z); v[7] = f2bf(y.w);
    *(short8*)(wfrag + c * 8) = v;
}

// ---------------- K1: fused [gemm | bucket] ----------------
// Blocks 0..781: 64 rows of Wh = feat @ W^T (bf16 MFMA), fused el/er.
//   Full-tile MLP: each lane issues its 16 feat float4 loads up front,
//   wfrag staged to LDS in the same vmcnt window, one barrier, then the
//   kt-loop runs from registers + LDS only.
// Blocks 782..1172: level-1 bucket scatter; src/dst read once as int4
//   batches into registers, packed word = src | (d&255)<<16 | (d>>8)<<24.
__global__ __launch_bounds__(256) void k_main(const float* __restrict__ feat,
                                              const unsigned short* __restrict__ wfrag,
                                              const float* __restrict__ att_w,
                                              unsigned short* __restrict__ whb,
                                              float* __restrict__ el,
                                              float* __restrict__ er,
                                              const int* __restrict__ src,
                                              const int* __restrict__ dst,
                                              int* __restrict__ cnt,
                                              unsigned* __restrict__ pairs) {
    __shared__ unsigned short wlds[16384];  // 32 KB (gemm); aliased by bucket
    const int tid = threadIdx.x;

    if (blockIdx.x >= GEMM_BLOCKS) {
        // ---- bucket part ----
        int* lhist = (int*)wlds;
        int* lcur  = lhist + 256;
        const int bbeg = (blockIdx.x - GEMM_BLOCKS) * EPB;

        unsigned wreg[16];
        #pragma unroll
        for (int j = 0; j < 4; ++j) {
            int e0 = bbeg + j * 1024 + tid * 4;
            if (e0 + 3 < N_EDGES) {
                int4 dv = *(const int4*)(dst + e0);
                int4 sv = *(const int4*)(src + e0);
                wreg[j*4+0] = (unsigned)sv.x | ((unsigned)(dv.x & 255) << 16) | ((unsigned)(dv.x >> 8) << 24);
                wreg[j*4+1] = (unsigned)sv.y | ((unsigned)(dv.y & 255) << 16) | ((unsigned)(dv.y >> 8) << 24);
                wreg[j*4+2] = (unsigned)sv.z | ((unsigned)(dv.z & 255) << 16) | ((unsigned)(dv.z >> 8) << 24);
                wreg[j*4+3] = (unsigned)sv.w | ((unsigned)(dv.w & 255) << 16) | ((unsigned)(dv.w >> 8) << 24);
            } else {
                #pragma unroll
                for (int k = 0; k < 4; ++k) {
                    int e = e0 + k;
                    if (e < N_EDGES) {
                        int d = dst[e];
                        wreg[j*4+k] = (unsigned)src[e] | ((unsigned)(d & 255) << 16) | ((unsigned)(d >> 8) << 24);
                    } else wreg[j*4+k] = 0xFF000000u;  // sentinel
                }
            }
        }
        for (int i = tid; i < NBUCKETS; i += 256) lhist[i] = 0;
        __syncthreads();
        #pragma unroll
        for (int k = 0; k < 16; ++k) {
            unsigned b = wreg[k] >> 24;
            if (b < NBUCKETS) atomicAdd(&lhist[b], 1);
        }
        __syncthreads();
        for (int i = tid; i < NBUCKETS; i += 256) {
            int c = lhist[i];
            lcur[i] = c ? (i * CAP + atomicAdd(&cnt[i], c)) : 0;
        }
        __syncthreads();
        #pragma unroll
        for (int k = 0; k < 16; ++k) {
            unsigned wv = wreg[k];
            unsigned b = wv >> 24;
            if (b < NBUCKETS) {
                int pos = atomicAdd(&lcur[b], 1);
                pairs[pos] = wv & 0x00FFFFFFu;
            }
        }
        return;
    }

    // ---- gemm part: wave = 16 rows x 64 cols ----
    const int l = tid & 63, w = tid >> 6;
    const int l15 = l & 15, lg = l >> 4;
    const int wbase = blockIdx.x * 64 + w * 16;
    int ar = wbase + l15; if (ar > N_NODES - 1) ar = N_NODES - 1;
    const float* fbase = feat + (size_t)ar * IN_F + 8 * lg;

    // issue ALL 16 feat loads (full-tile MLP)
    float4 f[16];
    #pragma unroll
    for (int kt = 0; kt < 8; ++kt) {
        f[2*kt]   = *(const float4*)(fbase + kt * 32);
        f[2*kt+1] = *(const float4*)(fbase + kt * 32 + 4);
    }
    // stage wfrag -> LDS in the same vmcnt window
    #pragma unroll
    for (int i = 0; i < 8; ++i) {
        int c = tid + 256 * i;
        *(short8*)(&wlds[c * 8]) = *(const short8*)(wfrag + c * 8);
    }
    __syncthreads();

    f32x4 acc[4];
    #pragma unroll
    for (int ct = 0; ct < 4; ++ct) acc[ct] = (f32x4){0.f, 0.f, 0.f, 0.f};

    #pragma unroll
    for (int kt = 0; kt < 8; ++kt) {
        float4 fa = f[2*kt], fb = f[2*kt+1];
        short8 af;
        af[0] = f2bf(fa.x); af[1] = f2bf(fa.y); af[2] = f2bf(fa.z); af[3] = f2bf(fa.w);
        af[4] = f2bf(fb.x); af[5] = f2bf(fb.y); af[6] = f2bf(fb.z); af[7] = f2bf(fb.w);
        short8 b0 = *(const short8*)(&wlds[((0 * 8 + kt) * 64 + l) * 8]);
        short8 b1 = *(const short8*)(&wlds[((1 * 8 + kt) * 64 + l) * 8]);
        short8 b2 = *(const short8*)(&wlds[((2 * 8 + kt) * 64 + l) * 8]);
        short8 b3 = *(const short8*)(&wlds[((3 * 8 + kt) * 64 + l) * 8]);
        acc[0] = __builtin_amdgcn_mfma_f32_16x16x32_bf16(af, b0, acc[0], 0, 0, 0);
        acc[1] = __builtin_amdgcn_mfma_f32_16x16x32_bf16(af, b1, acc[1], 0, 0, 0);
        acc[2] = __builtin_amdgcn_mfma_f32_16x16x32_bf16(af, b2, acc[2], 0, 0, 0);
        acc[3] = __builtin_amdgcn_mfma_f32_16x16x32_bf16(af, b3, acc[3], 0, 0, 0);
    }

    float asrc[4], adst[4];
    #pragma unroll
    for (int ct = 0; ct < 4; ++ct) {
        asrc[ct] = att_w[ct * 16 + l15];
        adst[ct] = att_w[64 + ct * 16 + l15];
    }
    #pragma unroll
    for (int j = 0; j < 4; ++j) {
        int row = wbase + lg * 4 + j;
        float vs = 0.f, vd = 0.f;
        #pragma unroll
        for (int ct = 0; ct < 4; ++ct) {
            float v = acc[ct][j];
            vs += v * asrc[ct];
            vd += v * adst[ct];
            if (row < N_NODES) whb[(size_t)row * OUT_F + ct * 16 + l15] = f2bf(v);
        }
        vs += __shfl_xor(vs, 1); vd += __shfl_xor(vd, 1);
        vs += __shfl_xor(vs, 2); vd += __shfl_xor(vd, 2);
        vs += __shfl_xor(vs, 4); vd += __shfl_xor(vd, 4);
        vs += __shfl_xor(vs, 8); vd += __shfl_xor(vd, 8);
        if (l15 == 0 && row < N_NODES) { el[row] = vs; er[row] = vd; }
    }
}

// ---------------- K2: level-2 CSR build (one block per bucket) -----------
// csr word = src(16b) | p-as-bf16(16b), p = exp(leaky(el[src]+er[node])).
// Segments padded to multiples of 4 with zero entries for k_aggr.
__global__ __launch_bounds__(1024) void k_build(const int* __restrict__ cnt,
                                                const unsigned* __restrict__ pairs,
                                                const float* __restrict__ el,
                                                const float* __restrict__ er,
                                                int* __restrict__ offs,
                                                int* __restrict__ oend,
                                                unsigned* __restrict__ csr) {
    __shared__ int lcnt[256], ssc[256], lcur[256];
    __shared__ float ler[256];
    const int b = blockIdx.x;
    const int t = threadIdx.x;
    const int ebeg = b * CAP;
    const int nE = cnt[b];

    if (t < 256) {
        lcnt[t] = 0;
        int node = b * 256 + t;
        ler[t] = (node < N_NODES) ? er[node] : 0.f;
    }
    __syncthreads();
    for (int i = t; i < nE; i += 1024)
        atomicAdd(&lcnt[(pairs[ebeg + i] >> 16) & 255], 1);
    __syncthreads();
    if (t < 256) ssc[t] = (lcnt[t] + 3) & ~3;   // padded count
    __syncthreads();
    for (int d = 1; d < 256; d <<= 1) {
        int v = 0;
        if (t < 256 && t >= d) v = ssc[t - d];
        __syncthreads();
        if (t < 256) ssc[t] += v;
        __syncthreads();
    }
    if (t < 256) {
        int pc = (lcnt[t] + 3) & ~3;
        int base = ssc[t] - pc;               // 4-aligned
        lcur[t] = base;
        int node = b * 256 + t;
        if (node < N_NODES) { offs[node] = ebeg + base; oend[node] = ebeg + base + pc; }
        for (int k = lcnt[t]; k < pc; ++k) csr[ebeg + base + k] = 0;  // pad
    }
    __syncthreads();
    for (int i = t; i < nE; i += 1024) {
        unsigned v = pairs[ebeg + i];
        int n8 = (v >> 16) & 255;
        int s = v & 0xFFFFu;
        float e = el[s] + ler[n8];
        e = (e > 0.f) ? e : 0.2f * e;
        float p = __expf(e);
        int pos = atomicAdd(&lcur[n8], 1);
        csr[ebeg + pos] = (unsigned)s | ((unsigned)f2bf(p) << 16);
    }
}

// ---------------- K3: per-node gather — 4 edges per VMEM ----------------
__global__ __launch_bounds__(256) void k_aggr(const int* __restrict__ offs,
                                              const int* __restrict__ oend,
                                              const unsigned* __restrict__ csr,
                                              const unsigned short* __restrict__ whb,
                                              const float* __restrict__ bias,
                                              float* __restrict__ out) {
    const int wid = __builtin_amdgcn_readfirstlane(threadIdx.x >> 6);
    const int node = blockIdx.x * 4 + wid;
    const int lane = threadIdx.x & 63;
    const int fg = lane & 15, es = lane >> 4;
    const int beg = offs[node], end = oend[node];

    float acc0 = 0.f, acc1 = 0.f, acc2 = 0.f, acc3 = 0.f, den = 0.f;
    #pragma unroll 2
    for (int j = beg; j < end; j += 4) {
        unsigned e = csr[j + es];
        float p = __uint_as_float(e & 0xFFFF0000u);
        const unsigned short* wp = whb + (size_t)(e & 0xFFFFu) * OUT_F + fg * 4;
        ushort4 wv = *(const ushort4*)wp;
        den += p;
        acc0 = fmaf(p, bf2f((unsigned)wv.x), acc0);
        acc1 = fmaf(p, bf2f((unsigned)wv.y), acc1);
        acc2 = fmaf(p, bf2f((unsigned)wv.z), acc2);
        acc3 = fmaf(p, bf2f((unsigned)wv.w), acc3);
    }
    acc0 += __shfl_xor(acc0, 16); acc0 += __shfl_xor(acc0, 32);
    acc1 += __shfl_xor(acc1, 16); acc1 += __shfl_xor(acc1, 32);
    acc2 += __shfl_xor(acc2, 16); acc2 += __shfl_xor(acc2, 32);
    acc3 += __shfl_xor(acc3, 16); acc3 += __shfl_xor(acc3, 32);
    den  += __shfl_xor(den, 16);  den  += __shfl_xor(den, 32);

    if (es == 0) {
        float inv = (end > beg) ? 1.f / den : 0.f;
        ushort4 wn = *(const ushort4*)(whb + (size_t)node * OUT_F + fg * 4);
        float4 b4 = *(const float4*)(bias + fg * 4);
        float h0 = acc0 * inv + bf2f((unsigned)wn.x) + b4.x;
        float h1 = acc1 * inv + bf2f((unsigned)wn.y) + b4.y;
        float h2 = acc2 * inv + bf2f((unsigned)wn.z) + b4.z;
        float h3 = acc3 * inv + bf2f((unsigned)wn.w) + b4.w;
        h0 = (h0 > 0.f) ? h0 : __expf(h0) - 1.f;
        h1 = (h1 > 0.f) ? h1 : __expf(h1) - 1.f;
        h2 = (h2 > 0.f) ? h2 : __expf(h2) - 1.f;
        h3 = (h3 > 0.f) ? h3 : __expf(h3) - 1.f;
        *(float4*)(out + (size_t)node * OUT_F + fg * 4) = make_float4(h0, h1, h2, h3);
    }
}

extern "C" void kernel_launch(void* const* d_in, const int* in_sizes, int n_in,
                              void* d_out, int out_size, void* d_ws, size_t ws_size,
                              hipStream_t stream) {
    const float* feat  = (const float*)d_in[0];
    const float* W     = (const float*)d_in[1];
    const float* att_w = (const float*)d_in[2];
    const float* bias  = (const float*)d_in[3];
    const int*   src   = (const int*)d_in[4];
    const int*   dst   = (const int*)d_in[5];
    float* out = (float*)d_out;

    // workspace layout (4-byte words)
    unsigned short* whb = (unsigned short*)d_ws;          // 1,600,000 words
    unsigned short* wfrag = whb + 3200000;                // 8,192 words (32 KB)
    float* el      = (float*)d_ws + 1600000 + 8192;       // 50,048
    float* er      = el + 50048;                          // 50,048
    int*   offs    = (int*)(er + 50048);                  // 50,048
    int*   oend    = offs + 50048;                        // 50,048
    int*   cnt     = oend + 50048;                        // 512
    unsigned* pairs = (unsigned*)(cnt + 512);             // 196*10240 = 2,007,040 words
    unsigned* csr   = pairs + NBUCKETS * CAP;             // 2,007,040 words
    // total ~23.5 MB

    k_prep<<<8, 256, 0, stream>>>(W, wfrag, cnt);
    k_main<<<GEMM_BLOCKS + BK_BLOCKS, 256, 0, stream>>>(feat, wfrag, att_w, whb, el, er,
                                                        src, dst, cnt, pairs);
    k_build<<<NBUCKETS, 1024, 0, stream>>>(cnt, pairs, el, er, offs, oend, csr);
    k_aggr<<<N_NODES / 4, 256, 0, stream>>>(offs, oend, csr, whb, bias, out);
}

// Round 10
// 81.852 us; speedup vs baseline: 8.3311x; 1.0647x over previous
//
#include <hip/hip_runtime.h>
#include <hip/hip_bf16.h>
#include <math.h>

#define N_NODES 50000
#define N_EDGES 1600000
#define IN_F 256
#define OUT_F 64

#define NBUCKETS 196        // bucket = dst >> 8 (256 nodes each)
#define CAP 10752           // per-bucket capacity (mean 8192 + pad ~896 + slack), /8 ok
#define GEMM_BLOCKS 782     // 64 rows each
#define BK_BLOCKS 391       // 4096 edges each
#define EPB 4096

typedef short short8 __attribute__((ext_vector_type(8)));
typedef unsigned short ushort8v __attribute__((ext_vector_type(8)));
typedef float f32x4 __attribute__((ext_vector_type(4)));

__device__ __forceinline__ unsigned short f2bf(float f) {
    union { __hip_bfloat16 h; unsigned short u; } v;
    v.h = __float2bfloat16(f);
    return v.u;
}
__device__ __forceinline__ float bf2f(unsigned u) {
    return __uint_as_float(u << 16);
}

// ---------------- K0: prep — W -> fragment-ordered bf16 wfrag; zero cnt ---
__global__ __launch_bounds__(256) void k_prep(const float* __restrict__ W,
                                              unsigned short* __restrict__ wfrag,
                                              int* __restrict__ cnt) {
    const int tid = threadIdx.x;
    if (blockIdx.x == 0 && tid < NBUCKETS) cnt[tid] = 0;
    int c = blockIdx.x * 256 + tid;
    int ct = c >> 9, kt = (c >> 6) & 7, cl = c & 63;
    int col = ct * 16 + (cl & 15);
    int kb = kt * 32 + 8 * (cl >> 4);
    const float* p = W + col * 256 + kb;
    float4 x = *(const float4*)p;
    float4 y = *(const float4*)(p + 4);
    short8 v;
    v[0] = f2bf(x.x); v[1] = f2bf(x.y); v[2] = f2bf(x.z); v[3] = f2bf(x.w);
    v[4] = f2bf(y.x); v[5] = f2bf(y.y); v[6] = f2bf(y.z); v[7] = f2bf(y.w);
    *(short8*)(wfrag + c * 8) = v;
}

// ---------------- K1: fused [gemm | bucket] ----------------
__global__ __launch_bounds__(256) void k_main(const float* __restrict__ feat,
                                              const unsigned short* __restrict__ wfrag,
                                              const float* __restrict__ att_w,
                                              unsigned short* __restrict__ whb,
                                              float* __restrict__ el,
                                              float* __restrict__ er,
                                              const int* __restrict__ src,
                                              const int* __restrict__ dst,
                                              int* __restrict__ cnt,
                                              unsigned* __restrict__ pairs) {
    __shared__ unsigned short wlds[16384];  // 32 KB (gemm); aliased by bucket
    const int tid = threadIdx.x;

    if (blockIdx.x >= GEMM_BLOCKS) {
        // ---- bucket part ----
        int* lhist = (int*)wlds;
        int* lcur  = lhist + 256;
        const int bbeg = (blockIdx.x - GEMM_BLOCKS) * EPB;

        unsigned wreg[16];
        #pragma unroll
        for (int j = 0; j < 4; ++j) {
            int e0 = bbeg + j * 1024 + tid * 4;
            if (e0 + 3 < N_EDGES) {
                int4 dv = *(const int4*)(dst + e0);
                int4 sv = *(const int4*)(src + e0);
                wreg[j*4+0] = (unsigned)sv.x | ((unsigned)(dv.x & 255) << 16) | ((unsigned)(dv.x >> 8) << 24);
                wreg[j*4+1] = (unsigned)sv.y | ((unsigned)(dv.y & 255) << 16) | ((unsigned)(dv.y >> 8) << 24);
                wreg[j*4+2] = (unsigned)sv.z | ((unsigned)(dv.z & 255) << 16) | ((unsigned)(dv.z >> 8) << 24);
                wreg[j*4+3] = (unsigned)sv.w | ((unsigned)(dv.w & 255) << 16) | ((unsigned)(dv.w >> 8) << 24);
            } else {
                #pragma unroll
                for (int k = 0; k < 4; ++k) {
                    int e = e0 + k;
                    if (e < N_EDGES) {
                        int d = dst[e];
                        wreg[j*4+k] = (unsigned)src[e] | ((unsigned)(d & 255) << 16) | ((unsigned)(d >> 8) << 24);
                    } else wreg[j*4+k] = 0xFF000000u;  // sentinel
                }
            }
        }
        for (int i = tid; i < NBUCKETS; i += 256) lhist[i] = 0;
        __syncthreads();
        #pragma unroll
        for (int k = 0; k < 16; ++k) {
            unsigned b = wreg[k] >> 24;
            if (b < NBUCKETS) atomicAdd(&lhist[b], 1);
        }
        __syncthreads();
        for (int i = tid; i < NBUCKETS; i += 256) {
            int c = lhist[i];
            lcur[i] = c ? (i * CAP + atomicAdd(&cnt[i], c)) : 0;
        }
        __syncthreads();
        #pragma unroll
        for (int k = 0; k < 16; ++k) {
            unsigned wv = wreg[k];
            unsigned b = wv >> 24;
            if (b < NBUCKETS) {
                int pos = atomicAdd(&lcur[b], 1);
                pairs[pos] = wv & 0x00FFFFFFu;
            }
        }
        return;
    }

    // ---- gemm part: wave = 16 rows x 64 cols ----
    const int l = tid & 63, w = tid >> 6;
    const int l15 = l & 15, lg = l >> 4;
    const int wbase = blockIdx.x * 64 + w * 16;
    int ar = wbase + l15; if (ar > N_NODES - 1) ar = N_NODES - 1;
    const float* fbase = feat + (size_t)ar * IN_F + 8 * lg;

    // issue ALL 16 feat loads (full-tile MLP)
    float4 f[16];
    #pragma unroll
    for (int kt = 0; kt < 8; ++kt) {
        f[2*kt]   = *(const float4*)(fbase + kt * 32);
        f[2*kt+1] = *(const float4*)(fbase + kt * 32 + 4);
    }
    // stage wfrag -> LDS in the same vmcnt window
    #pragma unroll
    for (int i = 0; i < 8; ++i) {
        int c = tid + 256 * i;
        *(short8*)(&wlds[c * 8]) = *(const short8*)(wfrag + c * 8);
    }
    __builtin_amdgcn_sched_barrier(0);   // pin: no load sinks below this point
    __syncthreads();

    f32x4 acc[4];
    #pragma unroll
    for (int ct = 0; ct < 4; ++ct) acc[ct] = (f32x4){0.f, 0.f, 0.f, 0.f};

    #pragma unroll
    for (int kt = 0; kt < 8; ++kt) {
        float4 fa = f[2*kt], fb = f[2*kt+1];
        short8 af;
        af[0] = f2bf(fa.x); af[1] = f2bf(fa.y); af[2] = f2bf(fa.z); af[3] = f2bf(fa.w);
        af[4] = f2bf(fb.x); af[5] = f2bf(fb.y); af[6] = f2bf(fb.z); af[7] = f2bf(fb.w);
        short8 b0 = *(const short8*)(&wlds[((0 * 8 + kt) * 64 + l) * 8]);
        short8 b1 = *(const short8*)(&wlds[((1 * 8 + kt) * 64 + l) * 8]);
        short8 b2 = *(const short8*)(&wlds[((2 * 8 + kt) * 64 + l) * 8]);
        short8 b3 = *(const short8*)(&wlds[((3 * 8 + kt) * 64 + l) * 8]);
        acc[0] = __builtin_amdgcn_mfma_f32_16x16x32_bf16(af, b0, acc[0], 0, 0, 0);
        acc[1] = __builtin_amdgcn_mfma_f32_16x16x32_bf16(af, b1, acc[1], 0, 0, 0);
        acc[2] = __builtin_amdgcn_mfma_f32_16x16x32_bf16(af, b2, acc[2], 0, 0, 0);
        acc[3] = __builtin_amdgcn_mfma_f32_16x16x32_bf16(af, b3, acc[3], 0, 0, 0);
    }

    float asrc[4], adst[4];
    #pragma unroll
    for (int ct = 0; ct < 4; ++ct) {
        asrc[ct] = att_w[ct * 16 + l15];
        adst[ct] = att_w[64 + ct * 16 + l15];
    }
    #pragma unroll
    for (int j = 0; j < 4; ++j) {
        int row = wbase + lg * 4 + j;
        float vs = 0.f, vd = 0.f;
        #pragma unroll
        for (int ct = 0; ct < 4; ++ct) {
            float v = acc[ct][j];
            vs += v * asrc[ct];
            vd += v * adst[ct];
            if (row < N_NODES) whb[(size_t)row * OUT_F + ct * 16 + l15] = f2bf(v);
        }
        vs += __shfl_xor(vs, 1); vd += __shfl_xor(vd, 1);
        vs += __shfl_xor(vs, 2); vd += __shfl_xor(vd, 2);
        vs += __shfl_xor(vs, 4); vd += __shfl_xor(vd, 4);
        vs += __shfl_xor(vs, 8); vd += __shfl_xor(vd, 8);
        if (l15 == 0 && row < N_NODES) { el[row] = vs; er[row] = vd; }
    }
}

// ---------------- K2: level-2 CSR build (one block per bucket) -----------
// csr word = src(16b) | p-as-bf16(16b), p = exp(leaky(el[src]+er[node])).
// Segments padded to multiples of 8 with zero entries for k_aggr.
__global__ __launch_bounds__(1024) void k_build(const int* __restrict__ cnt,
                                                const unsigned* __restrict__ pairs,
                                                const float* __restrict__ el,
                                                const float* __restrict__ er,
                                                int* __restrict__ offs,
                                                int* __restrict__ oend,
                                                unsigned* __restrict__ csr) {
    __shared__ int lcnt[256], ssc[256], lcur[256];
    __shared__ float ler[256];
    const int b = blockIdx.x;
    const int t = threadIdx.x;
    const int ebeg = b * CAP;
    const int nE = cnt[b];

    if (t < 256) {
        lcnt[t] = 0;
        int node = b * 256 + t;
        ler[t] = (node < N_NODES) ? er[node] : 0.f;
    }
    __syncthreads();
    for (int i = t; i < nE; i += 1024)
        atomicAdd(&lcnt[(pairs[ebeg + i] >> 16) & 255], 1);
    __syncthreads();
    if (t < 256) ssc[t] = (lcnt[t] + 7) & ~7;   // padded count (x8)
    __syncthreads();
    for (int d = 1; d < 256; d <<= 1) {
        int v = 0;
        if (t < 256 && t >= d) v = ssc[t - d];
        __syncthreads();
        if (t < 256) ssc[t] += v;
        __syncthreads();
    }
    if (t < 256) {
        int pc = (lcnt[t] + 7) & ~7;
        int base = ssc[t] - pc;               // 8-aligned
        lcur[t] = base;
        int node = b * 256 + t;
        if (node < N_NODES) { offs[node] = ebeg + base; oend[node] = ebeg + base + pc; }
        for (int k = lcnt[t]; k < pc; ++k) csr[ebeg + base + k] = 0;  // pad
    }
    __syncthreads();
    for (int i = t; i < nE; i += 1024) {
        unsigned v = pairs[ebeg + i];
        int n8 = (v >> 16) & 255;
        int s = v & 0xFFFFu;
        float e = el[s] + ler[n8];
        e = (e > 0.f) ? e : 0.2f * e;
        float p = __expf(e);
        int pos = atomicAdd(&lcur[n8], 1);
        csr[ebeg + pos] = (unsigned)s | ((unsigned)f2bf(p) << 16);
    }
}

// ---------------- K3: per-node gather — 8 edges per VMEM ----------------
// Wave per node. lane = (edge-slot es = l>>3, feature-group fg = l&7).
// csr[j+es] is a broadcast 32B load; each lane loads ushort8 (16B) of its
// slot's Wh row -> one wave VMEM covers 8 rows. Segments are 8-padded so
// the loop is branch-free. p unpacks from the lane's own csr word.
__global__ __launch_bounds__(256) void k_aggr(const int* __restrict__ offs,
                                              const int* __restrict__ oend,
                                              const unsigned* __restrict__ csr,
                                              const unsigned short* __restrict__ whb,
                                              const float* __restrict__ bias,
                                              float* __restrict__ out) {
    const int wid = __builtin_amdgcn_readfirstlane(threadIdx.x >> 6);
    const int node = blockIdx.x * 4 + wid;
    const int lane = threadIdx.x & 63;
    const int fg = lane & 7, es = lane >> 3;
    const int beg = offs[node], end = oend[node];

    float acc[8] = {0.f, 0.f, 0.f, 0.f, 0.f, 0.f, 0.f, 0.f};
    float den = 0.f;
    #pragma unroll 2
    for (int j = beg; j < end; j += 8) {
        unsigned e = csr[j + es];
        float p = __uint_as_float(e & 0xFFFF0000u);
        const unsigned short* wp = whb + (size_t)(e & 0xFFFFu) * OUT_F + fg * 8;
        ushort8v wv = *(const ushort8v*)wp;
        den += p;
        #pragma unroll
        for (int i = 0; i < 8; ++i) acc[i] = fmaf(p, bf2f((unsigned)wv[i]), acc[i]);
    }
    #pragma unroll
    for (int i = 0; i < 8; ++i) {
        acc[i] += __shfl_xor(acc[i], 8);
        acc[i] += __shfl_xor(acc[i], 16);
        acc[i] += __shfl_xor(acc[i], 32);
    }
    den += __shfl_xor(den, 8); den += __shfl_xor(den, 16); den += __shfl_xor(den, 32);

    if (es == 0) {
        float inv = (end > beg) ? 1.f / den : 0.f;
        ushort8v wn = *(const ushort8v*)(whb + (size_t)node * OUT_F + fg * 8);
        float4 b0 = *(const float4*)(bias + fg * 8);
        float4 b1 = *(const float4*)(bias + fg * 8 + 4);
        float h[8];
        h[0] = acc[0] * inv + bf2f((unsigned)wn[0]) + b0.x;
        h[1] = acc[1] * inv + bf2f((unsigned)wn[1]) + b0.y;
        h[2] = acc[2] * inv + bf2f((unsigned)wn[2]) + b0.z;
        h[3] = acc[3] * inv + bf2f((unsigned)wn[3]) + b0.w;
        h[4] = acc[4] * inv + bf2f((unsigned)wn[4]) + b1.x;
        h[5] = acc[5] * inv + bf2f((unsigned)wn[5]) + b1.y;
        h[6] = acc[6] * inv + bf2f((unsigned)wn[6]) + b1.z;
        h[7] = acc[7] * inv + bf2f((unsigned)wn[7]) + b1.w;
        #pragma unroll
        for (int i = 0; i < 8; ++i) h[i] = (h[i] > 0.f) ? h[i] : __expf(h[i]) - 1.f;
        float* op = out + (size_t)node * OUT_F + fg * 8;
        *(float4*)op = make_float4(h[0], h[1], h[2], h[3]);
        *(float4*)(op + 4) = make_float4(h[4], h[5], h[6], h[7]);
    }
}

extern "C" void kernel_launch(void* const* d_in, const int* in_sizes, int n_in,
                              void* d_out, int out_size, void* d_ws, size_t ws_size,
                              hipStream_t stream) {
    const float* feat  = (const float*)d_in[0];
    const float* W     = (const float*)d_in[1];
    const float* att_w = (const float*)d_in[2];
    const float* bias  = (const float*)d_in[3];
    const int*   src   = (const int*)d_in[4];
    const int*   dst   = (const int*)d_in[5];
    float* out = (float*)d_out;

    // workspace layout (4-byte words)
    unsigned short* whb = (unsigned short*)d_ws;          // 1,600,000 words
    unsigned short* wfrag = whb + 3200000;                // 8,192 words (32 KB)
    float* el      = (float*)d_ws + 1600000 + 8192;       // 50,048
    float* er      = el + 50048;                          // 50,048
    int*   offs    = (int*)(er + 50048);                  // 50,048
    int*   oend    = offs + 50048;                        // 50,048
    int*   cnt     = oend + 50048;                        // 512
    unsigned* pairs = (unsigned*)(cnt + 512);             // 196*10752 = 2,107,392 words
    unsigned* csr   = pairs + NBUCKETS * CAP;             // 2,107,392 words
    // total ~24.3 MB

    k_prep<<<8, 256, 0, stream>>>(W, wfrag, cnt);
    k_main<<<GEMM_BLOCKS + BK_BLOCKS, 256, 0, stream>>>(feat, wfrag, att_w, whb, el, er,
                                                        src, dst, cnt, pairs);
    k_build<<<NBUCKETS, 1024, 0, stream>>>(cnt, pairs, el, er, offs, oend, csr);
    k_aggr<<<N_NODES / 4, 256, 0, stream>>>(offs, oend, csr, whb, bias, out);
}